// Round 3
// baseline (447.639 us; speedup 1.0000x reference)
//
#include <hip/hip_runtime.h>
#include <hip/hip_bf16.h>

// Problem constants
#define B_   16
#define C_   64
#define G_   256
#define P_   4096
#define W_   1024
#define H_   256
#define WQ_  256
#define M_   (B_ * P_)   // 65536 flattened (b,p) rows

typedef __attribute__((ext_vector_type(8))) short bf16x8;   // MFMA A/B frag (4 VGPRs)
typedef __attribute__((ext_vector_type(4))) float f32x4;    // MFMA C/D frag

// fp32 -> bf16 (RNE) split helpers
__device__ __forceinline__ ushort f2bf(float x) {
    union { float f; unsigned u; } v; v.f = x;
    return (ushort)((v.u + 0x7FFFu + ((v.u >> 16) & 1u)) >> 16);
}
__device__ __forceinline__ float bf2f(ushort h) {
    union { unsigned u; float f; } v; v.u = ((unsigned)h) << 16;
    return v.f;
}
__device__ __forceinline__ void split2(float x, ushort& hi, ushort& lo) {
    hi = f2bf(x);
    lo = f2bf(x - bf2f(hi));
}

// ---------------------------------------------------------------------------
// convT: src[K][N] fp32 -> dh/dl[N][K] bf16 hi/lo planes (transposed)
// ---------------------------------------------------------------------------
__global__ __launch_bounds__(256) void convT_kernel(
    const float* __restrict__ src, ushort* __restrict__ dh,
    ushort* __restrict__ dl, int K, int N)
{
    __shared__ float tile[64][65];
    const int nb = N >> 6;
    const int k0 = (blockIdx.x / nb) * 64;
    const int n0 = (blockIdx.x % nb) * 64;
    const int t = threadIdx.x;
    #pragma unroll
    for (int i = 0; i < 16; ++i) {
        int e = i * 256 + t;
        int kr = e >> 6, nc = e & 63;
        tile[nc][kr] = src[(size_t)(k0 + kr) * N + n0 + nc];
    }
    __syncthreads();
    #pragma unroll
    for (int i = 0; i < 16; ++i) {
        int e = i * 256 + t;
        int nc = e >> 6, kr = e & 63;
        ushort h, l; split2(tile[nc][kr], h, l);
        size_t o = (size_t)(n0 + nc) * K + k0 + kr;
        dh[o] = h; dl[o] = l;
    }
}

// ---------------------------------------------------------------------------
// Kernel 1: prep — c = cx@Wc+bc, g = gx@Wg+bg, base = c@W1c + g@W1g + b1
// ---------------------------------------------------------------------------
__global__ __launch_bounds__(256) void prep_kernel(
    const float* __restrict__ cx, const float* __restrict__ gx,
    const float* __restrict__ Wc, const float* __restrict__ bc,
    const float* __restrict__ Wg, const float* __restrict__ bg,
    const float* __restrict__ W1, const float* __restrict__ b1,
    float* __restrict__ base_out)
{
    const int b = blockIdx.x;
    const int t = threadIdx.x;
    __shared__ float cxl[C_], gxl[G_], cl[C_], gl[G_];

    if (t < C_) cxl[t] = cx[b * C_ + t];
    gxl[t] = gx[b * G_ + t];
    __syncthreads();

    if (t < C_) {
        float acc = bc[t];
        #pragma unroll 4
        for (int i = 0; i < C_; ++i) acc += cxl[i] * Wc[i * C_ + t];
        cl[t] = acc;
    }
    {
        float acc = bg[t];
        #pragma unroll 4
        for (int i = 0; i < G_; ++i) acc += gxl[i] * Wg[i * G_ + t];
        gl[t] = acc;
    }
    __syncthreads();

    float acc = b1[t];
    #pragma unroll 4
    for (int i = 0; i < C_; ++i) acc += cl[i] * W1[i * H_ + t];
    #pragma unroll 4
    for (int i = 0; i < G_; ++i) acc += gl[i] * W1[(C_ + i) * H_ + t];
    base_out[b * H_ + t] = acc;
}

// ---------------------------------------------------------------------------
// Kernel 2: w GEMM via split-bf16 MFMA, T14 software pipeline.
// M=65536,K=1024,N=256. 128x128 tile, BK=32, 4 waves (2x2), 16x16x32 MFMA.
// Pipeline: loads for tile k+1 issued before MFMA of tile k (in-flight overlap).
// grid = (M/128)*(N/128) = 1024
// ---------------------------------------------------------------------------
__global__ __launch_bounds__(256) void gemm_w_mfma(
    const float* __restrict__ A,      // wx  M x 1024
    const ushort* __restrict__ BTh,   // WwT hi [256][1024]
    const ushort* __restrict__ BTl,   // WwT lo
    const float* __restrict__ bw,
    float* __restrict__ Cout)         // w  M x 256
{
    __shared__ __align__(16) ushort Ah[128 * 32], Al[128 * 32];
    __shared__ __align__(16) ushort Bh[128 * 32], Bl[128 * 32];
    const int t = threadIdx.x;
    const int nblk = blockIdx.x & 1, mblk = blockIdx.x >> 1;
    const int row0 = mblk * 128, col0 = nblk * 128;
    const int lane = t & 63, wave = t >> 6;
    const int wm = wave >> 1, wn = wave & 1;
    const int l15 = lane & 15, lq = lane >> 4;

    // staging coords
    const int s_ar = t >> 3;             // A row base (0..31), +32*i
    const int s_ak = (t & 7) * 4;        // A k offset (floats)
    const int s_bc = t >> 2;             // B col base (0..63), +64*i
    const int s_bk = (t & 3) * 8;        // B k offset (ushorts)

    f32x4 acc[4][4];
    #pragma unroll
    for (int m = 0; m < 4; ++m)
        #pragma unroll
        for (int n = 0; n < 4; ++n) acc[m][n] = (f32x4){0.f, 0.f, 0.f, 0.f};

    // pipeline registers
    float4 pa[4];
    uint4  pbh[2], pbl[2];

    auto load_tiles = [&](int k0) {
        #pragma unroll
        for (int i = 0; i < 4; ++i) {
            const int r = s_ar + 32 * i;
            pa[i] = *(const float4*)(A + (size_t)(row0 + r) * W_ + k0 + s_ak);
        }
        #pragma unroll
        for (int i = 0; i < 2; ++i) {
            const int c = s_bc + 64 * i;
            pbh[i] = *(const uint4*)(BTh + (size_t)(col0 + c) * W_ + k0 + s_bk);
            pbl[i] = *(const uint4*)(BTl + (size_t)(col0 + c) * W_ + k0 + s_bk);
        }
    };

    load_tiles(0);

    for (int k0 = 0; k0 < W_; k0 += 32) {
        if (k0) __syncthreads();       // prev tile's frag reads complete
        // convert + store staged regs to LDS (compiler waits vmcnt here)
        #pragma unroll
        for (int i = 0; i < 4; ++i) {
            const int r = s_ar + 32 * i;
            ushort4 hv, lv;
            split2(pa[i].x, hv.x, lv.x); split2(pa[i].y, hv.y, lv.y);
            split2(pa[i].z, hv.z, lv.z); split2(pa[i].w, hv.w, lv.w);
            const int byte = (r * 64 + s_ak * 2) ^ ((r & 7) << 4);
            *(ushort4*)((char*)Ah + byte) = hv;
            *(ushort4*)((char*)Al + byte) = lv;
        }
        #pragma unroll
        for (int i = 0; i < 2; ++i) {
            const int c = s_bc + 64 * i;
            const int byte = (c * 64 + s_bk * 2) ^ ((c & 7) << 4);
            *(uint4*)((char*)Bh + byte) = pbh[i];
            *(uint4*)((char*)Bl + byte) = pbl[i];
        }
        __syncthreads();
        // issue next tile's global loads — in flight during MFMA below
        if (k0 + 32 < W_) load_tiles(k0 + 32);

        bf16x8 afh[4], afl[4], bfh[4], bfl[4];
        #pragma unroll
        for (int m = 0; m < 4; ++m) {
            const int r = wm * 64 + m * 16 + l15;
            const int byte = (r * 64 + lq * 16) ^ ((r & 7) << 4);
            afh[m] = *(const bf16x8*)((const char*)Ah + byte);
            afl[m] = *(const bf16x8*)((const char*)Al + byte);
        }
        #pragma unroll
        for (int n = 0; n < 4; ++n) {
            const int c = wn * 64 + n * 16 + l15;
            const int byte = (c * 64 + lq * 16) ^ ((c & 7) << 4);
            bfh[n] = *(const bf16x8*)((const char*)Bh + byte);
            bfl[n] = *(const bf16x8*)((const char*)Bl + byte);
        }
        #pragma unroll
        for (int m = 0; m < 4; ++m)
            #pragma unroll
            for (int n = 0; n < 4; ++n) {
                acc[m][n] = __builtin_amdgcn_mfma_f32_16x16x32_bf16(afh[m], bfh[n], acc[m][n], 0, 0, 0);
                acc[m][n] = __builtin_amdgcn_mfma_f32_16x16x32_bf16(afh[m], bfl[n], acc[m][n], 0, 0, 0);
                acc[m][n] = __builtin_amdgcn_mfma_f32_16x16x32_bf16(afl[m], bfh[n], acc[m][n], 0, 0, 0);
            }
    }

    // epilogue: C[row][col] = acc + bw[col]
    float bwv[4];
    #pragma unroll
    for (int n = 0; n < 4; ++n) bwv[n] = bw[col0 + wn * 64 + n * 16 + l15];
    #pragma unroll
    for (int m = 0; m < 4; ++m)
        #pragma unroll
        for (int reg = 0; reg < 4; ++reg) {
            const size_t r = (size_t)row0 + wm * 64 + m * 16 + lq * 4 + reg;
            #pragma unroll
            for (int n = 0; n < 4; ++n)
                Cout[r * WQ_ + col0 + wn * 64 + n * 16 + l15] = acc[m][n][reg] + bwv[n];
        }
}

// ---------------------------------------------------------------------------
// Kernel 3: scores via split-bf16 MFMA + fused relu/dot(W2) epilogue, pipelined.
// M=65536,K=256(q),N=256(h). BM=64, BN=256, 4 waves (1x4 over N), BK=32.
// grid = M/64 = 1024
// ---------------------------------------------------------------------------
__global__ __launch_bounds__(256) void gemm_scores_mfma(
    const float* __restrict__ A,      // w M x 256
    const ushort* __restrict__ BTh,   // W1wT hi [256][256]
    const ushort* __restrict__ BTl,
    const float* __restrict__ base_,  // B_ x 256
    const float* __restrict__ W2,     // 256
    const float* __restrict__ b2,     // 1
    float* __restrict__ scores)       // M
{
    __shared__ __align__(16) ushort Ah[64 * 32], Al[64 * 32];
    __shared__ __align__(16) ushort Bh[256 * 32], Bl[256 * 32];
    __shared__ float red[4][64];
    const int t = threadIdx.x;
    const int row0 = blockIdx.x * 64;
    const int b = blockIdx.x >> 6;            // 4096/64 blocks per batch
    const int lane = t & 63, wave = t >> 6;   // wave = 64-col strip of H
    const int l15 = lane & 15, lq = lane >> 4;

    const int s_ar = t >> 3;
    const int s_ak = (t & 7) * 4;
    const int s_bc = t >> 2;
    const int s_bk = (t & 3) * 8;

    f32x4 acc[4][4];
    #pragma unroll
    for (int m = 0; m < 4; ++m)
        #pragma unroll
        for (int n = 0; n < 4; ++n) acc[m][n] = (f32x4){0.f, 0.f, 0.f, 0.f};

    // pipeline registers
    float4 pa[2];
    uint4  pbh[4], pbl[4];

    auto load_tiles = [&](int k0) {
        #pragma unroll
        for (int i = 0; i < 2; ++i) {
            const int r = s_ar + 32 * i;
            pa[i] = *(const float4*)(A + (size_t)(row0 + r) * H_ + k0 + s_ak);
        }
        #pragma unroll
        for (int i = 0; i < 4; ++i) {
            const int c = s_bc + 64 * i;
            pbh[i] = *(const uint4*)(BTh + (size_t)c * H_ + k0 + s_bk);
            pbl[i] = *(const uint4*)(BTl + (size_t)c * H_ + k0 + s_bk);
        }
    };

    load_tiles(0);

    for (int k0 = 0; k0 < H_; k0 += 32) {
        if (k0) __syncthreads();
        #pragma unroll
        for (int i = 0; i < 2; ++i) {
            const int r = s_ar + 32 * i;
            ushort4 hv, lv;
            split2(pa[i].x, hv.x, lv.x); split2(pa[i].y, hv.y, lv.y);
            split2(pa[i].z, hv.z, lv.z); split2(pa[i].w, hv.w, lv.w);
            const int byte = (r * 64 + s_ak * 2) ^ ((r & 7) << 4);
            *(ushort4*)((char*)Ah + byte) = hv;
            *(ushort4*)((char*)Al + byte) = lv;
        }
        #pragma unroll
        for (int i = 0; i < 4; ++i) {
            const int c = s_bc + 64 * i;
            const int byte = (c * 64 + s_bk * 2) ^ ((c & 7) << 4);
            *(uint4*)((char*)Bh + byte) = pbh[i];
            *(uint4*)((char*)Bl + byte) = pbl[i];
        }
        __syncthreads();
        if (k0 + 32 < H_) load_tiles(k0 + 32);

        bf16x8 afh[4], afl[4], bfh[4], bfl[4];
        #pragma unroll
        for (int m = 0; m < 4; ++m) {
            const int r = m * 16 + l15;
            const int byte = (r * 64 + lq * 16) ^ ((r & 7) << 4);
            afh[m] = *(const bf16x8*)((const char*)Ah + byte);
            afl[m] = *(const bf16x8*)((const char*)Al + byte);
        }
        #pragma unroll
        for (int n = 0; n < 4; ++n) {
            const int c = wave * 64 + n * 16 + l15;
            const int byte = (c * 64 + lq * 16) ^ ((c & 7) << 4);
            bfh[n] = *(const bf16x8*)((const char*)Bh + byte);
            bfl[n] = *(const bf16x8*)((const char*)Bl + byte);
        }
        #pragma unroll
        for (int m = 0; m < 4; ++m)
            #pragma unroll
            for (int n = 0; n < 4; ++n) {
                acc[m][n] = __builtin_amdgcn_mfma_f32_16x16x32_bf16(afh[m], bfh[n], acc[m][n], 0, 0, 0);
                acc[m][n] = __builtin_amdgcn_mfma_f32_16x16x32_bf16(afh[m], bfl[n], acc[m][n], 0, 0, 0);
                acc[m][n] = __builtin_amdgcn_mfma_f32_16x16x32_bf16(afl[m], bfh[n], acc[m][n], 0, 0, 0);
            }
    }

    // epilogue: scores[row] = sum_h relu(acc + base) * W2  (+ b2)
    float basev[4], w2v[4];
    #pragma unroll
    for (int n = 0; n < 4; ++n) {
        const int col = wave * 64 + n * 16 + l15;
        basev[n] = base_[b * H_ + col];
        w2v[n] = W2[col];
    }
    __syncthreads();
    #pragma unroll
    for (int m = 0; m < 4; ++m)
        #pragma unroll
        for (int reg = 0; reg < 4; ++reg) {
            float s = 0.f;
            #pragma unroll
            for (int n = 0; n < 4; ++n) {
                float h = acc[m][n][reg] + basev[n];
                h = fmaxf(h, 0.f);
                s += h * w2v[n];
            }
            // reduce over the 16 cols held by lanes sharing lq
            s += __shfl_xor(s, 1, 64);
            s += __shfl_xor(s, 2, 64);
            s += __shfl_xor(s, 4, 64);
            s += __shfl_xor(s, 8, 64);
            if (l15 == 0) red[wave][m * 16 + lq * 4 + reg] = s;
        }
    __syncthreads();
    if (t < 64) {
        scores[row0 + t] = red[0][t] + red[1][t] + red[2][t] + red[3][t] + b2[0];
    }
}

// ---------------------------------------------------------------------------
// Kernel 4: softmax stats per b — m = max_p s, z = sum_p exp(s-m)
// ---------------------------------------------------------------------------
__global__ __launch_bounds__(256) void softmax_stats_kernel(
    const float* __restrict__ scores, float* __restrict__ mz)
{
    const int b = blockIdx.x;
    const int t = threadIdx.x;
    __shared__ float red[8];

    float m = -1e30f;
    for (int p = t; p < P_; p += 256) m = fmaxf(m, scores[b * P_ + p]);
    #pragma unroll
    for (int d = 1; d < 64; d <<= 1) m = fmaxf(m, __shfl_xor(m, d, 64));
    if ((t & 63) == 0) red[t >> 6] = m;
    __syncthreads();
    if (t == 0) red[4] = fmaxf(fmaxf(red[0], red[1]), fmaxf(red[2], red[3]));
    __syncthreads();
    m = red[4];
    __syncthreads();

    float z = 0.f;
    for (int p = t; p < P_; p += 256) z += expf(scores[b * P_ + p] - m);
    #pragma unroll
    for (int d = 1; d < 64; d <<= 1) z += __shfl_xor(z, d, 64);
    if ((t & 63) == 0) red[t >> 6] = z;
    __syncthreads();
    if (t == 0) { mz[2 * b] = m; mz[2 * b + 1] = red[0] + red[1] + red[2] + red[3]; }
}

// ---------------------------------------------------------------------------
// Kernel 5: weighted partial sums over 128-row slices (float4-vectorized)
// grid = B_*32, 256 threads: rg = t>>6 picks 32-row subgroup, (t&63)*4 = q4
// ---------------------------------------------------------------------------
__global__ __launch_bounds__(256) void weighted_partial_kernel(
    const float* __restrict__ wmat, const float* __restrict__ scores,
    const float* __restrict__ mz, float* __restrict__ part)
{
    const int blk = blockIdx.x;
    const int b   = blk >> 5;
    const int sl  = blk & 31;
    const int t   = threadIdx.x;
    const int rg  = t >> 6;
    const int q4  = (t & 63) * 4;
    const float m = mz[2 * b];
    __shared__ float red[4][WQ_];

    float4 acc = {0.f, 0.f, 0.f, 0.f};
    const int p0 = sl * 128 + rg * 32;
    for (int p = p0; p < p0 + 32; ++p) {
        const float e = expf(scores[b * P_ + p] - m);
        const float4 v = *(const float4*)(wmat + ((size_t)b * P_ + p) * WQ_ + q4);
        acc.x += e * v.x; acc.y += e * v.y; acc.z += e * v.z; acc.w += e * v.w;
    }
    *(float4*)&red[rg][q4] = acc;
    __syncthreads();
    part[(size_t)(b * 32 + sl) * WQ_ + t] =
        red[0][t] + red[1][t] + red[2][t] + red[3][t];
}

// ---------------------------------------------------------------------------
// Kernel 6: finalize
// ---------------------------------------------------------------------------
__global__ __launch_bounds__(256) void finalize_kernel(
    const float* __restrict__ part, const float* __restrict__ mz,
    float* __restrict__ out)
{
    const int b = blockIdx.x;
    const int t = threadIdx.x;
    const float z = mz[2 * b + 1];
    float acc = 0.f;
    #pragma unroll
    for (int sl = 0; sl < 32; ++sl) acc += part[(size_t)(b * 32 + sl) * WQ_ + t];
    out[b * WQ_ + t] = acc / z;
}

// ---------------------------------------------------------------------------
extern "C" void kernel_launch(void* const* d_in, const int* in_sizes, int n_in,
                              void* d_out, int out_size, void* d_ws, size_t ws_size,
                              hipStream_t stream) {
    const float* cx = (const float*)d_in[0];
    const float* gx = (const float*)d_in[1];
    const float* wx = (const float*)d_in[2];
    const float* Wc = (const float*)d_in[3];
    const float* bc = (const float*)d_in[4];
    const float* Wg = (const float*)d_in[5];
    const float* bg = (const float*)d_in[6];
    const float* Ww = (const float*)d_in[7];
    const float* bw = (const float*)d_in[8];
    const float* W1 = (const float*)d_in[9];
    const float* b1 = (const float*)d_in[10];
    const float* W2 = (const float*)d_in[11];
    const float* b2 = (const float*)d_in[12];
    float* out = (float*)d_out;

    // workspace layout
    float* ws        = (float*)d_ws;
    float* ws_w      = ws;                               // M_*WQ_
    float* ws_scores = ws_w + (size_t)M_ * WQ_;          // M_
    float* ws_base   = ws_scores + M_;                   // B_*H_
    float* ws_mz     = ws_base + B_ * H_;                // 2*B_
    float* ws_part   = ws_mz + 2 * B_;                   // B_*32*WQ_
    ushort* WwTh     = (ushort*)(ws_part + B_ * 32 * WQ_);
    ushort* WwTl     = WwTh + (size_t)W_ * WQ_;
    ushort* W1Th     = WwTl + (size_t)W_ * WQ_;
    ushort* W1Tl     = W1Th + (size_t)H_ * H_;

    convT_kernel<<<(W_ / 64) * (WQ_ / 64), 256, 0, stream>>>(Ww, WwTh, WwTl, W_, WQ_);
    convT_kernel<<<(H_ / 64) * (H_ / 64), 256, 0, stream>>>(
        W1 + (size_t)(C_ + G_) * H_, W1Th, W1Tl, H_, H_);

    prep_kernel<<<B_, 256, 0, stream>>>(cx, gx, Wc, bc, Wg, bg, W1, b1, ws_base);

    gemm_w_mfma<<<(M_ / 128) * (WQ_ / 128), 256, 0, stream>>>(wx, WwTh, WwTl, bw, ws_w);

    gemm_scores_mfma<<<M_ / 64, 256, 0, stream>>>(
        ws_w, W1Th, W1Tl, ws_base, W2, b2, ws_scores);

    softmax_stats_kernel<<<B_, 256, 0, stream>>>(ws_scores, ws_mz);

    weighted_partial_kernel<<<B_ * 32, 256, 0, stream>>>(ws_w, ws_scores, ws_mz, ws_part);

    finalize_kernel<<<B_, 256, 0, stream>>>(ws_part, ws_mz, out);
}

// Round 5
// 445.071 us; speedup vs baseline: 1.0058x; 1.0058x over previous
//
#include <hip/hip_runtime.h>
#include <hip/hip_bf16.h>

// Problem constants
#define B_   16
#define C_   64
#define G_   256
#define P_   4096
#define W_   1024
#define H_   256
#define WQ_  256
#define M_   (B_ * P_)   // 65536 flattened (b,p) rows

typedef __attribute__((ext_vector_type(8))) short bf16x8;   // MFMA A/B frag (4 VGPRs)
typedef __attribute__((ext_vector_type(4))) float f32x4;    // MFMA C/D frag

// fp32 -> bf16 (RNE) split helpers
__device__ __forceinline__ ushort f2bf(float x) {
    union { float f; unsigned u; } v; v.f = x;
    return (ushort)((v.u + 0x7FFFu + ((v.u >> 16) & 1u)) >> 16);
}
__device__ __forceinline__ float bf2f(ushort h) {
    union { unsigned u; float f; } v; v.u = ((unsigned)h) << 16;
    return v.f;
}
__device__ __forceinline__ void split2(float x, ushort& hi, ushort& lo) {
    hi = f2bf(x);
    lo = f2bf(x - bf2f(hi));
}

// ---------------------------------------------------------------------------
// convT: src[K][N] fp32 -> dh/dl[N][K] bf16 hi/lo planes (transposed)
// ---------------------------------------------------------------------------
__global__ __launch_bounds__(256) void convT_kernel(
    const float* __restrict__ src, ushort* __restrict__ dh,
    ushort* __restrict__ dl, int K, int N)
{
    __shared__ float tile[64][65];
    const int nb = N >> 6;
    const int k0 = (blockIdx.x / nb) * 64;
    const int n0 = (blockIdx.x % nb) * 64;
    const int t = threadIdx.x;
    #pragma unroll
    for (int i = 0; i < 16; ++i) {
        int e = i * 256 + t;
        int kr = e >> 6, nc = e & 63;
        tile[nc][kr] = src[(size_t)(k0 + kr) * N + n0 + nc];
    }
    __syncthreads();
    #pragma unroll
    for (int i = 0; i < 16; ++i) {
        int e = i * 256 + t;
        int nc = e >> 6, kr = e & 63;
        ushort h, l; split2(tile[nc][kr], h, l);
        size_t o = (size_t)(n0 + nc) * K + k0 + kr;
        dh[o] = h; dl[o] = l;
    }
}

// ---------------------------------------------------------------------------
// Kernel 1: prep — c = cx@Wc+bc, g = gx@Wg+bg, base = c@W1c + g@W1g + b1
// ---------------------------------------------------------------------------
__global__ __launch_bounds__(256) void prep_kernel(
    const float* __restrict__ cx, const float* __restrict__ gx,
    const float* __restrict__ Wc, const float* __restrict__ bc,
    const float* __restrict__ Wg, const float* __restrict__ bg,
    const float* __restrict__ W1, const float* __restrict__ b1,
    float* __restrict__ base_out)
{
    const int b = blockIdx.x;
    const int t = threadIdx.x;
    __shared__ float cxl[C_], gxl[G_], cl[C_], gl[G_];

    if (t < C_) cxl[t] = cx[b * C_ + t];
    gxl[t] = gx[b * G_ + t];
    __syncthreads();

    if (t < C_) {
        float acc = bc[t];
        #pragma unroll 4
        for (int i = 0; i < C_; ++i) acc += cxl[i] * Wc[i * C_ + t];
        cl[t] = acc;
    }
    {
        float acc = bg[t];
        #pragma unroll 4
        for (int i = 0; i < G_; ++i) acc += gxl[i] * Wg[i * G_ + t];
        gl[t] = acc;
    }
    __syncthreads();

    float acc = b1[t];
    #pragma unroll 4
    for (int i = 0; i < C_; ++i) acc += cl[i] * W1[i * H_ + t];
    #pragma unroll 4
    for (int i = 0; i < G_; ++i) acc += gl[i] * W1[(C_ + i) * H_ + t];
    base_out[b * H_ + t] = acc;
}

// ---------------------------------------------------------------------------
// Kernel 2: w GEMM via split-bf16 MFMA, prefetch pipeline.
// M=65536,K=1024,N=256. 128x128 tile, BK=32, 4 waves (2x2), 16x16x32 MFMA.
// __launch_bounds__(256,2): pin 2 blocks/CU so the ~32 prefetch VGPRs are NOT
// spilled to scratch (R3 regression: compiler targeted 6 waves/EU -> 300MB
// scratch traffic). Loads for tile k+1 in flight during MFMA of tile k.
// grid = (M/128)*(N/128) = 1024
// ---------------------------------------------------------------------------
__global__ __launch_bounds__(256, 2) void gemm_w_mfma(
    const float* __restrict__ A,      // wx  M x 1024
    const ushort* __restrict__ BTh,   // WwT hi [256][1024]
    const ushort* __restrict__ BTl,   // WwT lo
    const float* __restrict__ bw,
    float* __restrict__ Cout)         // w  M x 256
{
    __shared__ __align__(16) ushort Ah[128 * 32], Al[128 * 32];
    __shared__ __align__(16) ushort Bh[128 * 32], Bl[128 * 32];
    const int t = threadIdx.x;
    const int nblk = blockIdx.x & 1, mblk = blockIdx.x >> 1;
    const int row0 = mblk * 128, col0 = nblk * 128;
    const int lane = t & 63, wave = t >> 6;
    const int wm = wave >> 1, wn = wave & 1;
    const int l15 = lane & 15, lq = lane >> 4;

    // staging coords
    const int s_ar = t >> 3;             // A row base (0..31), +32*i
    const int s_ak = (t & 7) * 4;        // A k offset (floats)
    const int s_bc = t >> 2;             // B col base (0..63), +64*i
    const int s_bk = (t & 3) * 8;        // B k offset (ushorts)

    f32x4 acc[4][4];
    #pragma unroll
    for (int m = 0; m < 4; ++m)
        #pragma unroll
        for (int n = 0; n < 4; ++n) acc[m][n] = (f32x4){0.f, 0.f, 0.f, 0.f};

    // pipeline registers (static-indexed everywhere)
    float4 pa[4];
    uint4  pbh[2], pbl[2];

#define LOADW(K0)                                                                \
    {                                                                            \
        _Pragma("unroll")                                                        \
        for (int i = 0; i < 4; ++i)                                              \
            pa[i] = *(const float4*)(A + (size_t)(row0 + s_ar + 32 * i) * W_     \
                                     + (K0) + s_ak);                             \
        _Pragma("unroll")                                                        \
        for (int i = 0; i < 2; ++i) {                                            \
            pbh[i] = *(const uint4*)(BTh + (size_t)(col0 + s_bc + 64 * i) * W_   \
                                     + (K0) + s_bk);                             \
            pbl[i] = *(const uint4*)(BTl + (size_t)(col0 + s_bc + 64 * i) * W_   \
                                     + (K0) + s_bk);                             \
        }                                                                        \
    }

    LOADW(0)

    for (int k0 = 0; k0 < W_; k0 += 32) {
        if (k0) __syncthreads();       // prev tile's frag reads complete
        // convert + store staged regs to LDS
        #pragma unroll
        for (int i = 0; i < 4; ++i) {
            const int r = s_ar + 32 * i;
            ushort4 hv, lv;
            split2(pa[i].x, hv.x, lv.x); split2(pa[i].y, hv.y, lv.y);
            split2(pa[i].z, hv.z, lv.z); split2(pa[i].w, hv.w, lv.w);
            const int byte = (r * 64 + s_ak * 2) ^ ((r & 7) << 4);
            *(ushort4*)((char*)Ah + byte) = hv;
            *(ushort4*)((char*)Al + byte) = lv;
        }
        #pragma unroll
        for (int i = 0; i < 2; ++i) {
            const int c = s_bc + 64 * i;
            const int byte = (c * 64 + s_bk * 2) ^ ((c & 7) << 4);
            *(uint4*)((char*)Bh + byte) = pbh[i];
            *(uint4*)((char*)Bl + byte) = pbl[i];
        }
        __syncthreads();
        // issue next tile's global loads — in flight during MFMA below
        if (k0 + 32 < W_) LOADW(k0 + 32)

        bf16x8 afh[4], afl[4], bfh[4], bfl[4];
        #pragma unroll
        for (int m = 0; m < 4; ++m) {
            const int r = wm * 64 + m * 16 + l15;
            const int byte = (r * 64 + lq * 16) ^ ((r & 7) << 4);
            afh[m] = *(const bf16x8*)((const char*)Ah + byte);
            afl[m] = *(const bf16x8*)((const char*)Al + byte);
        }
        #pragma unroll
        for (int n = 0; n < 4; ++n) {
            const int c = wn * 64 + n * 16 + l15;
            const int byte = (c * 64 + lq * 16) ^ ((c & 7) << 4);
            bfh[n] = *(const bf16x8*)((const char*)Bh + byte);
            bfl[n] = *(const bf16x8*)((const char*)Bl + byte);
        }
        #pragma unroll
        for (int m = 0; m < 4; ++m)
            #pragma unroll
            for (int n = 0; n < 4; ++n) {
                acc[m][n] = __builtin_amdgcn_mfma_f32_16x16x32_bf16(afh[m], bfh[n], acc[m][n], 0, 0, 0);
                acc[m][n] = __builtin_amdgcn_mfma_f32_16x16x32_bf16(afh[m], bfl[n], acc[m][n], 0, 0, 0);
                acc[m][n] = __builtin_amdgcn_mfma_f32_16x16x32_bf16(afl[m], bfh[n], acc[m][n], 0, 0, 0);
            }
    }
#undef LOADW

    // epilogue: C[row][col] = acc + bw[col]
    float bwv[4];
    #pragma unroll
    for (int n = 0; n < 4; ++n) bwv[n] = bw[col0 + wn * 64 + n * 16 + l15];
    #pragma unroll
    for (int m = 0; m < 4; ++m)
        #pragma unroll
        for (int reg = 0; reg < 4; ++reg) {
            const size_t r = (size_t)row0 + wm * 64 + m * 16 + lq * 4 + reg;
            #pragma unroll
            for (int n = 0; n < 4; ++n)
                Cout[r * WQ_ + col0 + wn * 64 + n * 16 + l15] = acc[m][n][reg] + bwv[n];
        }
}

// ---------------------------------------------------------------------------
// Kernel 3: scores via split-bf16 MFMA + fused relu/dot(W2) epilogue, pipelined.
// M=65536,K=256(q),N=256(h). BM=64, BN=256, 4 waves (1x4 over N), BK=32.
// grid = M/64 = 1024
// ---------------------------------------------------------------------------
__global__ __launch_bounds__(256, 2) void gemm_scores_mfma(
    const float* __restrict__ A,      // w M x 256
    const ushort* __restrict__ BTh,   // W1wT hi [256][256]
    const ushort* __restrict__ BTl,
    const float* __restrict__ base_,  // B_ x 256
    const float* __restrict__ W2,     // 256
    const float* __restrict__ b2,     // 1
    float* __restrict__ scores)       // M
{
    __shared__ __align__(16) ushort Ah[64 * 32], Al[64 * 32];
    __shared__ __align__(16) ushort Bh[256 * 32], Bl[256 * 32];
    __shared__ float red[4][64];
    const int t = threadIdx.x;
    const int row0 = blockIdx.x * 64;
    const int b = blockIdx.x >> 6;            // 4096/64 blocks per batch
    const int lane = t & 63, wave = t >> 6;   // wave = 64-col strip of H
    const int l15 = lane & 15, lq = lane >> 4;

    const int s_ar = t >> 3;
    const int s_ak = (t & 7) * 4;
    const int s_bc = t >> 2;
    const int s_bk = (t & 3) * 8;

    f32x4 acc[4][4];
    #pragma unroll
    for (int m = 0; m < 4; ++m)
        #pragma unroll
        for (int n = 0; n < 4; ++n) acc[m][n] = (f32x4){0.f, 0.f, 0.f, 0.f};

    // pipeline registers
    float4 pa[2];
    uint4  pbh[4], pbl[4];

#define LOADS(K0)                                                                \
    {                                                                            \
        _Pragma("unroll")                                                        \
        for (int i = 0; i < 2; ++i)                                              \
            pa[i] = *(const float4*)(A + (size_t)(row0 + s_ar + 32 * i) * H_     \
                                     + (K0) + s_ak);                             \
        _Pragma("unroll")                                                        \
        for (int i = 0; i < 4; ++i) {                                            \
            pbh[i] = *(const uint4*)(BTh + (size_t)(s_bc + 64 * i) * H_          \
                                     + (K0) + s_bk);                             \
            pbl[i] = *(const uint4*)(BTl + (size_t)(s_bc + 64 * i) * H_          \
                                     + (K0) + s_bk);                             \
        }                                                                        \
    }

    LOADS(0)

    for (int k0 = 0; k0 < H_; k0 += 32) {
        if (k0) __syncthreads();
        #pragma unroll
        for (int i = 0; i < 2; ++i) {
            const int r = s_ar + 32 * i;
            ushort4 hv, lv;
            split2(pa[i].x, hv.x, lv.x); split2(pa[i].y, hv.y, lv.y);
            split2(pa[i].z, hv.z, lv.z); split2(pa[i].w, hv.w, lv.w);
            const int byte = (r * 64 + s_ak * 2) ^ ((r & 7) << 4);
            *(ushort4*)((char*)Ah + byte) = hv;
            *(ushort4*)((char*)Al + byte) = lv;
        }
        #pragma unroll
        for (int i = 0; i < 4; ++i) {
            const int c = s_bc + 64 * i;
            const int byte = (c * 64 + s_bk * 2) ^ ((c & 7) << 4);
            *(uint4*)((char*)Bh + byte) = pbh[i];
            *(uint4*)((char*)Bl + byte) = pbl[i];
        }
        __syncthreads();
        if (k0 + 32 < H_) LOADS(k0 + 32)

        bf16x8 afh[4], afl[4], bfh[4], bfl[4];
        #pragma unroll
        for (int m = 0; m < 4; ++m) {
            const int r = m * 16 + l15;
            const int byte = (r * 64 + lq * 16) ^ ((r & 7) << 4);
            afh[m] = *(const bf16x8*)((const char*)Ah + byte);
            afl[m] = *(const bf16x8*)((const char*)Al + byte);
        }
        #pragma unroll
        for (int n = 0; n < 4; ++n) {
            const int c = wave * 64 + n * 16 + l15;
            const int byte = (c * 64 + lq * 16) ^ ((c & 7) << 4);
            bfh[n] = *(const bf16x8*)((const char*)Bh + byte);
            bfl[n] = *(const bf16x8*)((const char*)Bl + byte);
        }
        #pragma unroll
        for (int m = 0; m < 4; ++m)
            #pragma unroll
            for (int n = 0; n < 4; ++n) {
                acc[m][n] = __builtin_amdgcn_mfma_f32_16x16x32_bf16(afh[m], bfh[n], acc[m][n], 0, 0, 0);
                acc[m][n] = __builtin_amdgcn_mfma_f32_16x16x32_bf16(afh[m], bfl[n], acc[m][n], 0, 0, 0);
                acc[m][n] = __builtin_amdgcn_mfma_f32_16x16x32_bf16(afl[m], bfh[n], acc[m][n], 0, 0, 0);
            }
    }
#undef LOADS

    // epilogue: scores[row] = sum_h relu(acc + base) * W2  (+ b2)
    float basev[4], w2v[4];
    #pragma unroll
    for (int n = 0; n < 4; ++n) {
        const int col = wave * 64 + n * 16 + l15;
        basev[n] = base_[b * H_ + col];
        w2v[n] = W2[col];
    }
    __syncthreads();
    #pragma unroll
    for (int m = 0; m < 4; ++m)
        #pragma unroll
        for (int reg = 0; reg < 4; ++reg) {
            float s = 0.f;
            #pragma unroll
            for (int n = 0; n < 4; ++n) {
                float h = acc[m][n][reg] + basev[n];
                h = fmaxf(h, 0.f);
                s += h * w2v[n];
            }
            // reduce over the 16 cols held by lanes sharing lq
            s += __shfl_xor(s, 1, 64);
            s += __shfl_xor(s, 2, 64);
            s += __shfl_xor(s, 4, 64);
            s += __shfl_xor(s, 8, 64);
            if (l15 == 0) red[wave][m * 16 + lq * 4 + reg] = s;
        }
    __syncthreads();
    if (t < 64) {
        scores[row0 + t] = red[0][t] + red[1][t] + red[2][t] + red[3][t] + b2[0];
    }
}

// ---------------------------------------------------------------------------
// Kernel 4: softmax stats per b — m = max_p s, z = sum_p exp(s-m)
// ---------------------------------------------------------------------------
__global__ __launch_bounds__(256) void softmax_stats_kernel(
    const float* __restrict__ scores, float* __restrict__ mz)
{
    const int b = blockIdx.x;
    const int t = threadIdx.x;
    __shared__ float red[8];

    float m = -1e30f;
    for (int p = t; p < P_; p += 256) m = fmaxf(m, scores[b * P_ + p]);
    #pragma unroll
    for (int d = 1; d < 64; d <<= 1) m = fmaxf(m, __shfl_xor(m, d, 64));
    if ((t & 63) == 0) red[t >> 6] = m;
    __syncthreads();
    if (t == 0) red[4] = fmaxf(fmaxf(red[0], red[1]), fmaxf(red[2], red[3]));
    __syncthreads();
    m = red[4];
    __syncthreads();

    float z = 0.f;
    for (int p = t; p < P_; p += 256) z += expf(scores[b * P_ + p] - m);
    #pragma unroll
    for (int d = 1; d < 64; d <<= 1) z += __shfl_xor(z, d, 64);
    if ((t & 63) == 0) red[t >> 6] = z;
    __syncthreads();
    if (t == 0) { mz[2 * b] = m; mz[2 * b + 1] = red[0] + red[1] + red[2] + red[3]; }
}

// ---------------------------------------------------------------------------
// Kernel 5: weighted partial sums over 128-row slices (float4-vectorized)
// grid = B_*32, 256 threads: rg = t>>6 picks 32-row subgroup, (t&63)*4 = q4
// ---------------------------------------------------------------------------
__global__ __launch_bounds__(256) void weighted_partial_kernel(
    const float* __restrict__ wmat, const float* __restrict__ scores,
    const float* __restrict__ mz, float* __restrict__ part)
{
    const int blk = blockIdx.x;
    const int b   = blk >> 5;
    const int sl  = blk & 31;
    const int t   = threadIdx.x;
    const int rg  = t >> 6;
    const int q4  = (t & 63) * 4;
    const float m = mz[2 * b];
    __shared__ float red[4][WQ_];

    float4 acc = {0.f, 0.f, 0.f, 0.f};
    const int p0 = sl * 128 + rg * 32;
    for (int p = p0; p < p0 + 32; ++p) {
        const float e = expf(scores[b * P_ + p] - m);
        const float4 v = *(const float4*)(wmat + ((size_t)b * P_ + p) * WQ_ + q4);
        acc.x += e * v.x; acc.y += e * v.y; acc.z += e * v.z; acc.w += e * v.w;
    }
    *(float4*)&red[rg][q4] = acc;
    __syncthreads();
    part[(size_t)(b * 32 + sl) * WQ_ + t] =
        red[0][t] + red[1][t] + red[2][t] + red[3][t];
}

// ---------------------------------------------------------------------------
// Kernel 6: finalize
// ---------------------------------------------------------------------------
__global__ __launch_bounds__(256) void finalize_kernel(
    const float* __restrict__ part, const float* __restrict__ mz,
    float* __restrict__ out)
{
    const int b = blockIdx.x;
    const int t = threadIdx.x;
    const float z = mz[2 * b + 1];
    float acc = 0.f;
    #pragma unroll
    for (int sl = 0; sl < 32; ++sl) acc += part[(size_t)(b * 32 + sl) * WQ_ + t];
    out[b * WQ_ + t] = acc / z;
}

// ---------------------------------------------------------------------------
extern "C" void kernel_launch(void* const* d_in, const int* in_sizes, int n_in,
                              void* d_out, int out_size, void* d_ws, size_t ws_size,
                              hipStream_t stream) {
    const float* cx = (const float*)d_in[0];
    const float* gx = (const float*)d_in[1];
    const float* wx = (const float*)d_in[2];
    const float* Wc = (const float*)d_in[3];
    const float* bc = (const float*)d_in[4];
    const float* Wg = (const float*)d_in[5];
    const float* bg = (const float*)d_in[6];
    const float* Ww = (const float*)d_in[7];
    const float* bw = (const float*)d_in[8];
    const float* W1 = (const float*)d_in[9];
    const float* b1 = (const float*)d_in[10];
    const float* W2 = (const float*)d_in[11];
    const float* b2 = (const float*)d_in[12];
    float* out = (float*)d_out;

    // workspace layout
    float* ws        = (float*)d_ws;
    float* ws_w      = ws;                               // M_*WQ_
    float* ws_scores = ws_w + (size_t)M_ * WQ_;          // M_
    float* ws_base   = ws_scores + M_;                   // B_*H_
    float* ws_mz     = ws_base + B_ * H_;                // 2*B_
    float* ws_part   = ws_mz + 2 * B_;                   // B_*32*WQ_
    ushort* WwTh     = (ushort*)(ws_part + B_ * 32 * WQ_);
    ushort* WwTl     = WwTh + (size_t)W_ * WQ_;
    ushort* W1Th     = WwTl + (size_t)W_ * WQ_;
    ushort* W1Tl     = W1Th + (size_t)H_ * H_;

    convT_kernel<<<(W_ / 64) * (WQ_ / 64), 256, 0, stream>>>(Ww, WwTh, WwTl, W_, WQ_);
    convT_kernel<<<(H_ / 64) * (H_ / 64), 256, 0, stream>>>(
        W1 + (size_t)(C_ + G_) * H_, W1Th, W1Tl, H_, H_);

    prep_kernel<<<B_, 256, 0, stream>>>(cx, gx, Wc, bc, Wg, bg, W1, b1, ws_base);

    gemm_w_mfma<<<(M_ / 128) * (WQ_ / 128), 256, 0, stream>>>(wx, WwTh, WwTl, bw, ws_w);

    gemm_scores_mfma<<<M_ / 64, 256, 0, stream>>>(
        ws_w, W1Th, W1Tl, ws_base, W2, b2, ws_scores);

    softmax_stats_kernel<<<B_, 256, 0, stream>>>(ws_scores, ws_mz);

    weighted_partial_kernel<<<B_ * 32, 256, 0, stream>>>(ws_w, ws_scores, ws_mz, ws_part);

    finalize_kernel<<<B_, 256, 0, stream>>>(ws_part, ws_mz, out);
}

// Round 6
// 327.102 us; speedup vs baseline: 1.3685x; 1.3606x over previous
//
#include <hip/hip_runtime.h>
#include <hip/hip_bf16.h>

// Problem constants
#define B_   16
#define C_   64
#define G_   256
#define P_   4096
#define W_   1024
#define H_   256
#define WQ_  256
#define M_   (B_ * P_)   // 65536 flattened (b,p) rows

typedef __attribute__((ext_vector_type(8))) short bf16x8;   // MFMA A/B frag (4 VGPRs)
typedef __attribute__((ext_vector_type(4))) float f32x4;    // MFMA C/D frag

// fp32 -> bf16 (RNE) split helpers
__device__ __forceinline__ ushort f2bf(float x) {
    union { float f; unsigned u; } v; v.f = x;
    return (ushort)((v.u + 0x7FFFu + ((v.u >> 16) & 1u)) >> 16);
}
__device__ __forceinline__ float bf2f(ushort h) {
    union { unsigned u; float f; } v; v.u = ((unsigned)h) << 16;
    return v.f;
}
__device__ __forceinline__ void split2(float x, ushort& hi, ushort& lo) {
    hi = f2bf(x);
    lo = f2bf(x - bf2f(hi));
}

// ---------------------------------------------------------------------------
// convT: src[K][N] fp32 -> dh/dl[N][K] bf16 hi/lo planes (transposed)
// ---------------------------------------------------------------------------
__global__ __launch_bounds__(256) void convT_kernel(
    const float* __restrict__ src, ushort* __restrict__ dh,
    ushort* __restrict__ dl, int K, int N)
{
    __shared__ float tile[64][65];
    const int nb = N >> 6;
    const int k0 = (blockIdx.x / nb) * 64;
    const int n0 = (blockIdx.x % nb) * 64;
    const int t = threadIdx.x;
    #pragma unroll
    for (int i = 0; i < 16; ++i) {
        int e = i * 256 + t;
        int kr = e >> 6, nc = e & 63;
        tile[nc][kr] = src[(size_t)(k0 + kr) * N + n0 + nc];
    }
    __syncthreads();
    #pragma unroll
    for (int i = 0; i < 16; ++i) {
        int e = i * 256 + t;
        int nc = e >> 6, kr = e & 63;
        ushort h, l; split2(tile[nc][kr], h, l);
        size_t o = (size_t)(n0 + nc) * K + k0 + kr;
        dh[o] = h; dl[o] = l;
    }
}

// ---------------------------------------------------------------------------
// Kernel 1: prep — c = cx@Wc+bc, g = gx@Wg+bg, base = c@W1c + g@W1g + b1
// ---------------------------------------------------------------------------
__global__ __launch_bounds__(256) void prep_kernel(
    const float* __restrict__ cx, const float* __restrict__ gx,
    const float* __restrict__ Wc, const float* __restrict__ bc,
    const float* __restrict__ Wg, const float* __restrict__ bg,
    const float* __restrict__ W1, const float* __restrict__ b1,
    float* __restrict__ base_out)
{
    const int b = blockIdx.x;
    const int t = threadIdx.x;
    __shared__ float cxl[C_], gxl[G_], cl[C_], gl[G_];

    if (t < C_) cxl[t] = cx[b * C_ + t];
    gxl[t] = gx[b * G_ + t];
    __syncthreads();

    if (t < C_) {
        float acc = bc[t];
        #pragma unroll 4
        for (int i = 0; i < C_; ++i) acc += cxl[i] * Wc[i * C_ + t];
        cl[t] = acc;
    }
    {
        float acc = bg[t];
        #pragma unroll 4
        for (int i = 0; i < G_; ++i) acc += gxl[i] * Wg[i * G_ + t];
        gl[t] = acc;
    }
    __syncthreads();

    float acc = b1[t];
    #pragma unroll 4
    for (int i = 0; i < C_; ++i) acc += cl[i] * W1[i * H_ + t];
    #pragma unroll 4
    for (int i = 0; i < G_; ++i) acc += gl[i] * W1[(C_ + i) * H_ + t];
    base_out[b * H_ + t] = acc;
}

// ---------------------------------------------------------------------------
// Kernel 2: w GEMM via split-bf16 MFMA, full-N blocks.
// M=65536,K=1024,N=256. BM=128, BN=256(all), BK=32. 512 thr = 8 waves (2Mx4N),
// each wave 64x64 out = 4x4 frags of 16x16x32, 3 MFMA passes (AhBh,AhBl,AlBh).
// R2-style staging (load->convert->ds_write at loop top; NO reg prefetch — the
// scheduler sinks it, R3/R5 regression). Conversion VALU per thread halved vs
// R2 (512 thr share the same A tile) and A is read/converted once total.
// grid = M/128 = 512 = 2 blocks/CU * 256 CU.  LDS 48KB -> 2 blocks/CU.
// ---------------------------------------------------------------------------
__global__ __launch_bounds__(512) void gemm_w_mfma(
    const float* __restrict__ A,      // wx  M x 1024
    const ushort* __restrict__ BTh,   // WwT hi [256][1024]
    const ushort* __restrict__ BTl,   // WwT lo
    const float* __restrict__ bw,
    float* __restrict__ Cout)         // w  M x 256
{
    __shared__ __align__(16) ushort Ah[128 * 32], Al[128 * 32];   // 8KB each
    __shared__ __align__(16) ushort Bh[256 * 32], Bl[256 * 32];   // 16KB each
    const int t = threadIdx.x;
    const int row0 = blockIdx.x * 128;
    const int lane = t & 63, wave = t >> 6;
    const int wm = wave >> 2, wn = wave & 3;          // 2M x 4N waves
    const int l15 = lane & 15, lq = lane >> 4;

    // staging coords
    const int s_ar = t >> 2;             // A row (0..127)
    const int s_ak = (t & 3) * 8;        // A k offset (floats): 0,8,16,24
    const int s_bc = t & 255;            // B col (0..255)
    const int s_bk = (t >> 8) * 16;      // B k offset (ushorts): 0 or 16

    f32x4 acc[4][4];
    #pragma unroll
    for (int m = 0; m < 4; ++m)
        #pragma unroll
        for (int n = 0; n < 4; ++n) acc[m][n] = (f32x4){0.f, 0.f, 0.f, 0.f};

    for (int k0 = 0; k0 < W_; k0 += 32) {
        if (k0) __syncthreads();       // prev tile's frag reads complete
        // stage A: 8 floats/thread -> hi/lo bf16, swizzled
        {
            const float4 v0 = *(const float4*)(A + (size_t)(row0 + s_ar) * W_ + k0 + s_ak);
            const float4 v1 = *(const float4*)(A + (size_t)(row0 + s_ar) * W_ + k0 + s_ak + 4);
            ushort4 h0, l0, h1, l1;
            split2(v0.x, h0.x, l0.x); split2(v0.y, h0.y, l0.y);
            split2(v0.z, h0.z, l0.z); split2(v0.w, h0.w, l0.w);
            split2(v1.x, h1.x, l1.x); split2(v1.y, h1.y, l1.y);
            split2(v1.z, h1.z, l1.z); split2(v1.w, h1.w, l1.w);
            const int byte0 = (s_ar * 64 + s_ak * 2) ^ ((s_ar & 7) << 4);
            const int byte1 = (s_ar * 64 + s_ak * 2 + 8) ^ ((s_ar & 7) << 4);
            *(ushort4*)((char*)Ah + byte0) = h0;
            *(ushort4*)((char*)Ah + byte1) = h1;
            *(ushort4*)((char*)Al + byte0) = l0;
            *(ushort4*)((char*)Al + byte1) = l1;
        }
        // stage B: 2x uint4 per plane per thread, swizzled
        #pragma unroll
        for (int i = 0; i < 2; ++i) {
            const int kk = s_bk + i * 8;
            const int byte = (s_bc * 64 + kk * 2) ^ ((s_bc & 7) << 4);
            *(uint4*)((char*)Bh + byte) =
                *(const uint4*)(BTh + (size_t)s_bc * W_ + k0 + kk);
            *(uint4*)((char*)Bl + byte) =
                *(const uint4*)(BTl + (size_t)s_bc * W_ + k0 + kk);
        }
        __syncthreads();

        bf16x8 afh[4], afl[4], bfh[4], bfl[4];
        #pragma unroll
        for (int m = 0; m < 4; ++m) {
            const int r = wm * 64 + m * 16 + l15;
            const int byte = (r * 64 + lq * 16) ^ ((r & 7) << 4);
            afh[m] = *(const bf16x8*)((const char*)Ah + byte);
            afl[m] = *(const bf16x8*)((const char*)Al + byte);
        }
        #pragma unroll
        for (int n = 0; n < 4; ++n) {
            const int c = wn * 64 + n * 16 + l15;
            const int byte = (c * 64 + lq * 16) ^ ((c & 7) << 4);
            bfh[n] = *(const bf16x8*)((const char*)Bh + byte);
            bfl[n] = *(const bf16x8*)((const char*)Bl + byte);
        }
        #pragma unroll
        for (int m = 0; m < 4; ++m)
            #pragma unroll
            for (int n = 0; n < 4; ++n) {
                acc[m][n] = __builtin_amdgcn_mfma_f32_16x16x32_bf16(afh[m], bfh[n], acc[m][n], 0, 0, 0);
                acc[m][n] = __builtin_amdgcn_mfma_f32_16x16x32_bf16(afh[m], bfl[n], acc[m][n], 0, 0, 0);
                acc[m][n] = __builtin_amdgcn_mfma_f32_16x16x32_bf16(afl[m], bfh[n], acc[m][n], 0, 0, 0);
            }
    }

    // epilogue: C[row][col] = acc + bw[col]
    float bwv[4];
    #pragma unroll
    for (int n = 0; n < 4; ++n) bwv[n] = bw[wn * 64 + n * 16 + l15];
    #pragma unroll
    for (int m = 0; m < 4; ++m)
        #pragma unroll
        for (int reg = 0; reg < 4; ++reg) {
            const size_t r = (size_t)row0 + wm * 64 + m * 16 + lq * 4 + reg;
            #pragma unroll
            for (int n = 0; n < 4; ++n)
                Cout[r * WQ_ + wn * 64 + n * 16 + l15] = acc[m][n][reg] + bwv[n];
        }
}

// ---------------------------------------------------------------------------
// Kernel 3: scores via split-bf16 MFMA + fused relu/dot(W2) epilogue.
// M=65536,K=256(q),N=256(h). BM=128, BN=256(all), BK=32, 512 thr, 8 waves.
// grid = M/128 = 512
// ---------------------------------------------------------------------------
__global__ __launch_bounds__(512) void gemm_scores_mfma(
    const float* __restrict__ A,      // w M x 256
    const ushort* __restrict__ BTh,   // W1wT hi [256][256]
    const ushort* __restrict__ BTl,
    const float* __restrict__ base_,  // B_ x 256
    const float* __restrict__ W2,     // 256
    const float* __restrict__ b2,     // 1
    float* __restrict__ scores)       // M
{
    __shared__ __align__(16) ushort Ah[128 * 32], Al[128 * 32];
    __shared__ __align__(16) ushort Bh[256 * 32], Bl[256 * 32];
    __shared__ float red[4][128];
    const int t = threadIdx.x;
    const int row0 = blockIdx.x * 128;
    const int b = blockIdx.x >> 5;            // 32 blocks per batch
    const int lane = t & 63, wave = t >> 6;
    const int wm = wave >> 2, wn = wave & 3;
    const int l15 = lane & 15, lq = lane >> 4;

    const int s_ar = t >> 2;
    const int s_ak = (t & 3) * 8;
    const int s_bc = t & 255;
    const int s_bk = (t >> 8) * 16;

    f32x4 acc[4][4];
    #pragma unroll
    for (int m = 0; m < 4; ++m)
        #pragma unroll
        for (int n = 0; n < 4; ++n) acc[m][n] = (f32x4){0.f, 0.f, 0.f, 0.f};

    for (int k0 = 0; k0 < H_; k0 += 32) {
        if (k0) __syncthreads();
        {
            const float4 v0 = *(const float4*)(A + (size_t)(row0 + s_ar) * H_ + k0 + s_ak);
            const float4 v1 = *(const float4*)(A + (size_t)(row0 + s_ar) * H_ + k0 + s_ak + 4);
            ushort4 h0, l0, h1, l1;
            split2(v0.x, h0.x, l0.x); split2(v0.y, h0.y, l0.y);
            split2(v0.z, h0.z, l0.z); split2(v0.w, h0.w, l0.w);
            split2(v1.x, h1.x, l1.x); split2(v1.y, h1.y, l1.y);
            split2(v1.z, h1.z, l1.z); split2(v1.w, h1.w, l1.w);
            const int byte0 = (s_ar * 64 + s_ak * 2) ^ ((s_ar & 7) << 4);
            const int byte1 = (s_ar * 64 + s_ak * 2 + 8) ^ ((s_ar & 7) << 4);
            *(ushort4*)((char*)Ah + byte0) = h0;
            *(ushort4*)((char*)Ah + byte1) = h1;
            *(ushort4*)((char*)Al + byte0) = l0;
            *(ushort4*)((char*)Al + byte1) = l1;
        }
        #pragma unroll
        for (int i = 0; i < 2; ++i) {
            const int kk = s_bk + i * 8;
            const int byte = (s_bc * 64 + kk * 2) ^ ((s_bc & 7) << 4);
            *(uint4*)((char*)Bh + byte) =
                *(const uint4*)(BTh + (size_t)s_bc * H_ + k0 + kk);
            *(uint4*)((char*)Bl + byte) =
                *(const uint4*)(BTl + (size_t)s_bc * H_ + k0 + kk);
        }
        __syncthreads();

        bf16x8 afh[4], afl[4], bfh[4], bfl[4];
        #pragma unroll
        for (int m = 0; m < 4; ++m) {
            const int r = wm * 64 + m * 16 + l15;
            const int byte = (r * 64 + lq * 16) ^ ((r & 7) << 4);
            afh[m] = *(const bf16x8*)((const char*)Ah + byte);
            afl[m] = *(const bf16x8*)((const char*)Al + byte);
        }
        #pragma unroll
        for (int n = 0; n < 4; ++n) {
            const int c = wn * 64 + n * 16 + l15;
            const int byte = (c * 64 + lq * 16) ^ ((c & 7) << 4);
            bfh[n] = *(const bf16x8*)((const char*)Bh + byte);
            bfl[n] = *(const bf16x8*)((const char*)Bl + byte);
        }
        #pragma unroll
        for (int m = 0; m < 4; ++m)
            #pragma unroll
            for (int n = 0; n < 4; ++n) {
                acc[m][n] = __builtin_amdgcn_mfma_f32_16x16x32_bf16(afh[m], bfh[n], acc[m][n], 0, 0, 0);
                acc[m][n] = __builtin_amdgcn_mfma_f32_16x16x32_bf16(afh[m], bfl[n], acc[m][n], 0, 0, 0);
                acc[m][n] = __builtin_amdgcn_mfma_f32_16x16x32_bf16(afl[m], bfh[n], acc[m][n], 0, 0, 0);
            }
    }

    // epilogue: scores[row] = sum_h relu(acc + base) * W2  (+ b2)
    float basev[4], w2v[4];
    #pragma unroll
    for (int n = 0; n < 4; ++n) {
        const int col = wn * 64 + n * 16 + l15;
        basev[n] = base_[b * H_ + col];
        w2v[n] = W2[col];
    }
    __syncthreads();
    #pragma unroll
    for (int m = 0; m < 4; ++m)
        #pragma unroll
        for (int reg = 0; reg < 4; ++reg) {
            float s = 0.f;
            #pragma unroll
            for (int n = 0; n < 4; ++n) {
                float h = acc[m][n][reg] + basev[n];
                h = fmaxf(h, 0.f);
                s += h * w2v[n];
            }
            // reduce over the 16 cols held by lanes sharing lq
            s += __shfl_xor(s, 1, 64);
            s += __shfl_xor(s, 2, 64);
            s += __shfl_xor(s, 4, 64);
            s += __shfl_xor(s, 8, 64);
            if (l15 == 0) red[wn][wm * 64 + m * 16 + lq * 4 + reg] = s;
        }
    __syncthreads();
    if (t < 128) {
        scores[row0 + t] = red[0][t] + red[1][t] + red[2][t] + red[3][t] + b2[0];
    }
}

// ---------------------------------------------------------------------------
// Kernel 4: softmax stats per b — m = max_p s, z = sum_p exp(s-m)
// ---------------------------------------------------------------------------
__global__ __launch_bounds__(256) void softmax_stats_kernel(
    const float* __restrict__ scores, float* __restrict__ mz)
{
    const int b = blockIdx.x;
    const int t = threadIdx.x;
    __shared__ float red[8];

    float m = -1e30f;
    for (int p = t; p < P_; p += 256) m = fmaxf(m, scores[b * P_ + p]);
    #pragma unroll
    for (int d = 1; d < 64; d <<= 1) m = fmaxf(m, __shfl_xor(m, d, 64));
    if ((t & 63) == 0) red[t >> 6] = m;
    __syncthreads();
    if (t == 0) red[4] = fmaxf(fmaxf(red[0], red[1]), fmaxf(red[2], red[3]));
    __syncthreads();
    m = red[4];
    __syncthreads();

    float z = 0.f;
    for (int p = t; p < P_; p += 256) z += expf(scores[b * P_ + p] - m);
    #pragma unroll
    for (int d = 1; d < 64; d <<= 1) z += __shfl_xor(z, d, 64);
    if ((t & 63) == 0) red[t >> 6] = z;
    __syncthreads();
    if (t == 0) { mz[2 * b] = m; mz[2 * b + 1] = red[0] + red[1] + red[2] + red[3]; }
}

// ---------------------------------------------------------------------------
// Kernel 5: weighted partial sums over 128-row slices (float4-vectorized)
// ---------------------------------------------------------------------------
__global__ __launch_bounds__(256) void weighted_partial_kernel(
    const float* __restrict__ wmat, const float* __restrict__ scores,
    const float* __restrict__ mz, float* __restrict__ part)
{
    const int blk = blockIdx.x;
    const int b   = blk >> 5;
    const int sl  = blk & 31;
    const int t   = threadIdx.x;
    const int rg  = t >> 6;
    const int q4  = (t & 63) * 4;
    const float m = mz[2 * b];
    __shared__ float red[4][WQ_];

    float4 acc = {0.f, 0.f, 0.f, 0.f};
    const int p0 = sl * 128 + rg * 32;
    for (int p = p0; p < p0 + 32; ++p) {
        const float e = expf(scores[b * P_ + p] - m);
        const float4 v = *(const float4*)(wmat + ((size_t)b * P_ + p) * WQ_ + q4);
        acc.x += e * v.x; acc.y += e * v.y; acc.z += e * v.z; acc.w += e * v.w;
    }
    *(float4*)&red[rg][q4] = acc;
    __syncthreads();
    part[(size_t)(b * 32 + sl) * WQ_ + t] =
        red[0][t] + red[1][t] + red[2][t] + red[3][t];
}

// ---------------------------------------------------------------------------
// Kernel 6: finalize
// ---------------------------------------------------------------------------
__global__ __launch_bounds__(256) void finalize_kernel(
    const float* __restrict__ part, const float* __restrict__ mz,
    float* __restrict__ out)
{
    const int b = blockIdx.x;
    const int t = threadIdx.x;
    const float z = mz[2 * b + 1];
    float acc = 0.f;
    #pragma unroll
    for (int sl = 0; sl < 32; ++sl) acc += part[(size_t)(b * 32 + sl) * WQ_ + t];
    out[b * WQ_ + t] = acc / z;
}

// ---------------------------------------------------------------------------
extern "C" void kernel_launch(void* const* d_in, const int* in_sizes, int n_in,
                              void* d_out, int out_size, void* d_ws, size_t ws_size,
                              hipStream_t stream) {
    const float* cx = (const float*)d_in[0];
    const float* gx = (const float*)d_in[1];
    const float* wx = (const float*)d_in[2];
    const float* Wc = (const float*)d_in[3];
    const float* bc = (const float*)d_in[4];
    const float* Wg = (const float*)d_in[5];
    const float* bg = (const float*)d_in[6];
    const float* Ww = (const float*)d_in[7];
    const float* bw = (const float*)d_in[8];
    const float* W1 = (const float*)d_in[9];
    const float* b1 = (const float*)d_in[10];
    const float* W2 = (const float*)d_in[11];
    const float* b2 = (const float*)d_in[12];
    float* out = (float*)d_out;

    // workspace layout
    float* ws        = (float*)d_ws;
    float* ws_w      = ws;                               // M_*WQ_
    float* ws_scores = ws_w + (size_t)M_ * WQ_;          // M_
    float* ws_base   = ws_scores + M_;                   // B_*H_
    float* ws_mz     = ws_base + B_ * H_;                // 2*B_
    float* ws_part   = ws_mz + 2 * B_;                   // B_*32*WQ_
    ushort* WwTh     = (ushort*)(ws_part + B_ * 32 * WQ_);
    ushort* WwTl     = WwTh + (size_t)W_ * WQ_;
    ushort* W1Th     = WwTl + (size_t)W_ * WQ_;
    ushort* W1Tl     = W1Th + (size_t)H_ * H_;

    convT_kernel<<<(W_ / 64) * (WQ_ / 64), 256, 0, stream>>>(Ww, WwTh, WwTl, W_, WQ_);
    convT_kernel<<<(H_ / 64) * (H_ / 64), 256, 0, stream>>>(
        W1 + (size_t)(C_ + G_) * H_, W1Th, W1Tl, H_, H_);

    prep_kernel<<<B_, 256, 0, stream>>>(cx, gx, Wc, bc, Wg, bg, W1, b1, ws_base);

    gemm_w_mfma<<<M_ / 128, 512, 0, stream>>>(wx, WwTh, WwTl, bw, ws_w);

    gemm_scores_mfma<<<M_ / 128, 512, 0, stream>>>(
        ws_w, W1Th, W1Tl, ws_base, W2, b2, ws_scores);

    softmax_stats_kernel<<<B_, 256, 0, stream>>>(ws_scores, ws_mz);

    weighted_partial_kernel<<<B_ * 32, 256, 0, stream>>>(ws_w, ws_scores, ws_mz, ws_part);

    finalize_kernel<<<B_, 256, 0, stream>>>(ws_part, ws_mz, out);
}

// Round 7
// 233.730 us; speedup vs baseline: 1.9152x; 1.3995x over previous
//
#include <hip/hip_runtime.h>
#include <hip/hip_bf16.h>

// Problem constants
#define B_   16
#define C_   64
#define G_   256
#define P_   4096
#define W_   1024
#define H_   256
#define WQ_  256
#define M_   (B_ * P_)   // 65536 flattened (b,p) rows

typedef __attribute__((ext_vector_type(8))) _Float16 f16x8;  // MFMA A/B frag (4 VGPRs)
typedef __attribute__((ext_vector_type(4))) float    f32x4;  // MFMA C/D frag

// ---------------------------------------------------------------------------
// convT16: src[K][N] fp32 -> dst[N][K] fp16 (transposed, RNE via v_cvt_f16_f32)
// grid = (K/64)*(N/64), 256 threads
// ---------------------------------------------------------------------------
__global__ __launch_bounds__(256) void convT16_kernel(
    const float* __restrict__ src, ushort* __restrict__ dst, int K, int N)
{
    __shared__ float tile[64][65];
    const int nb = N >> 6;
    const int k0 = (blockIdx.x / nb) * 64;
    const int n0 = (blockIdx.x % nb) * 64;
    const int t = threadIdx.x;
    #pragma unroll
    for (int i = 0; i < 16; ++i) {
        int e = i * 256 + t;
        int kr = e >> 6, nc = e & 63;
        tile[nc][kr] = src[(size_t)(k0 + kr) * N + n0 + nc];
    }
    __syncthreads();
    #pragma unroll
    for (int i = 0; i < 16; ++i) {
        int e = i * 256 + t;
        int nc = e >> 6, kr = e & 63;
        union { _Float16 h; ushort u; } cv;
        cv.h = (_Float16)tile[nc][kr];
        dst[(size_t)(n0 + nc) * K + k0 + kr] = cv.u;
    }
}

// ---------------------------------------------------------------------------
// Kernel 1: prep — c = cx@Wc+bc, g = gx@Wg+bg, base = c@W1c + g@W1g + b1
// ---------------------------------------------------------------------------
__global__ __launch_bounds__(256) void prep_kernel(
    const float* __restrict__ cx, const float* __restrict__ gx,
    const float* __restrict__ Wc, const float* __restrict__ bc,
    const float* __restrict__ Wg, const float* __restrict__ bg,
    const float* __restrict__ W1, const float* __restrict__ b1,
    float* __restrict__ base_out)
{
    const int b = blockIdx.x;
    const int t = threadIdx.x;
    __shared__ float cxl[C_], gxl[G_], cl[C_], gl[G_];

    if (t < C_) cxl[t] = cx[b * C_ + t];
    gxl[t] = gx[b * G_ + t];
    __syncthreads();

    if (t < C_) {
        float acc = bc[t];
        #pragma unroll 4
        for (int i = 0; i < C_; ++i) acc += cxl[i] * Wc[i * C_ + t];
        cl[t] = acc;
    }
    {
        float acc = bg[t];
        #pragma unroll 4
        for (int i = 0; i < G_; ++i) acc += gxl[i] * Wg[i * G_ + t];
        gl[t] = acc;
    }
    __syncthreads();

    float acc = b1[t];
    #pragma unroll 4
    for (int i = 0; i < C_; ++i) acc += cl[i] * W1[i * H_ + t];
    #pragma unroll 4
    for (int i = 0; i < G_; ++i) acc += gl[i] * W1[(C_ + i) * H_ + t];
    base_out[b * H_ + t] = acc;
}

// ---------------------------------------------------------------------------
// Kernel 2: w GEMM, single-pass fp16 MFMA (16x16x32_f16).
// M=65536,K=1024,N=256. BM=128, BN=128, BK=64. 256 thr, 4 waves (2x2),
// wave = 64x64 out = 4x4 frags. R2-proven 2-barrier loop, stage-at-top,
// no reg prefetch (R3/R5: scheduler sinks it). A converted fp32->fp16 in
// staging (1 cvt/elem); B pre-converted fp16.
// grid = (M/128)*(N/128) = 1024
// ---------------------------------------------------------------------------
__global__ __launch_bounds__(256) void gemm_w_mfma(
    const float* __restrict__ A,      // wx  M x 1024 fp32
    const ushort* __restrict__ BT,    // WwT fp16 [256][1024]
    const float* __restrict__ bw,
    float* __restrict__ Cout)         // w  M x 256 fp32
{
    __shared__ __align__(16) ushort Ah[128 * 64];   // 16 KB
    __shared__ __align__(16) ushort Bh[128 * 64];   // 16 KB
    const int t = threadIdx.x;
    const int nblk = blockIdx.x & 1, mblk = blockIdx.x >> 1;
    const int row0 = mblk * 128, col0 = nblk * 128;
    const int lane = t & 63, wave = t >> 6;
    const int wm = wave >> 1, wn = wave & 1;
    const int l15 = lane & 15, lq = lane >> 4;

    const int s_r = t >> 3;            // row/col base 0..31 (+32*i)
    const int s_k = (t & 7) * 8;       // k chunk start (8 elems)

    f32x4 acc[4][4];
    #pragma unroll
    for (int m = 0; m < 4; ++m)
        #pragma unroll
        for (int n = 0; n < 4; ++n) acc[m][n] = (f32x4){0.f, 0.f, 0.f, 0.f};

    for (int k0 = 0; k0 < W_; k0 += 64) {
        if (k0) __syncthreads();
        #pragma unroll
        for (int i = 0; i < 4; ++i) {
            const int r = s_r + 32 * i;
            // A: 8 fp32 -> 8 fp16 (RNE), one b128 write
            const float4 v0 = *(const float4*)(A + (size_t)(row0 + r) * W_ + k0 + s_k);
            const float4 v1 = *(const float4*)(A + (size_t)(row0 + r) * W_ + k0 + s_k + 4);
            f16x8 h;
            h[0] = (_Float16)v0.x; h[1] = (_Float16)v0.y;
            h[2] = (_Float16)v0.z; h[3] = (_Float16)v0.w;
            h[4] = (_Float16)v1.x; h[5] = (_Float16)v1.y;
            h[6] = (_Float16)v1.z; h[7] = (_Float16)v1.w;
            const int bytea = (r * 128 + s_k * 2) ^ ((r & 7) << 4);
            *(f16x8*)((char*)Ah + bytea) = h;
            // B: already fp16, one uint4 copy
            const int byteb = (r * 128 + s_k * 2) ^ ((r & 7) << 4);
            *(uint4*)((char*)Bh + byteb) =
                *(const uint4*)(BT + (size_t)(col0 + r) * W_ + k0 + s_k);
        }
        __syncthreads();

        #pragma unroll
        for (int ks = 0; ks < 2; ++ks) {
            f16x8 af[4], bf[4];
            #pragma unroll
            for (int m = 0; m < 4; ++m) {
                const int r = wm * 64 + m * 16 + l15;
                const int byte = (r * 128 + ks * 64 + lq * 16) ^ ((r & 7) << 4);
                af[m] = *(const f16x8*)((const char*)Ah + byte);
            }
            #pragma unroll
            for (int n = 0; n < 4; ++n) {
                const int c = wn * 64 + n * 16 + l15;
                const int byte = (c * 128 + ks * 64 + lq * 16) ^ ((c & 7) << 4);
                bf[n] = *(const f16x8*)((const char*)Bh + byte);
            }
            #pragma unroll
            for (int m = 0; m < 4; ++m)
                #pragma unroll
                for (int n = 0; n < 4; ++n)
                    acc[m][n] = __builtin_amdgcn_mfma_f32_16x16x32_f16(
                        af[m], bf[n], acc[m][n], 0, 0, 0);
        }
    }

    // epilogue: C[row][col] = acc + bw[col]
    float bwv[4];
    #pragma unroll
    for (int n = 0; n < 4; ++n) bwv[n] = bw[col0 + wn * 64 + n * 16 + l15];
    #pragma unroll
    for (int m = 0; m < 4; ++m)
        #pragma unroll
        for (int reg = 0; reg < 4; ++reg) {
            const size_t r = (size_t)row0 + wm * 64 + m * 16 + lq * 4 + reg;
            #pragma unroll
            for (int n = 0; n < 4; ++n)
                Cout[r * WQ_ + col0 + wn * 64 + n * 16 + l15] = acc[m][n][reg] + bwv[n];
        }
}

// ---------------------------------------------------------------------------
// Kernel 3: scores, single-pass fp16 MFMA + fused relu/dot(W2) epilogue.
// M=65536,K=256(q),N=256(h). BM=128, BN=256(all), BK=32, 512 thr, 8 waves (2x4).
// grid = M/128 = 512
// ---------------------------------------------------------------------------
__global__ __launch_bounds__(512) void gemm_scores_mfma(
    const float* __restrict__ A,      // w M x 256 fp32
    const ushort* __restrict__ BT,    // W1wT fp16 [256][256]
    const float* __restrict__ base_,  // B_ x 256
    const float* __restrict__ W2,     // 256
    const float* __restrict__ b2,     // 1
    float* __restrict__ scores)       // M
{
    __shared__ __align__(16) ushort Ah[128 * 32];   // 8 KB
    __shared__ __align__(16) ushort Bh[256 * 32];   // 16 KB
    __shared__ float red[4][128];
    const int t = threadIdx.x;
    const int row0 = blockIdx.x * 128;
    const int b = blockIdx.x >> 5;            // 32 blocks per batch
    const int lane = t & 63, wave = t >> 6;
    const int wm = wave >> 2, wn = wave & 3;
    const int l15 = lane & 15, lq = lane >> 4;

    const int sa_r = t >> 2;            // A row 0..127
    const int sa_k = (t & 3) * 8;       // A k chunk (8 elems)
    const int sb_c = t >> 1;            // B col 0..255
    const int sb_k = (t & 1) * 16;      // B k half (16 elems)

    f32x4 acc[4][4];
    #pragma unroll
    for (int m = 0; m < 4; ++m)
        #pragma unroll
        for (int n = 0; n < 4; ++n) acc[m][n] = (f32x4){0.f, 0.f, 0.f, 0.f};

    for (int k0 = 0; k0 < H_; k0 += 32) {
        if (k0) __syncthreads();
        {
            const float4 v0 = *(const float4*)(A + (size_t)(row0 + sa_r) * H_ + k0 + sa_k);
            const float4 v1 = *(const float4*)(A + (size_t)(row0 + sa_r) * H_ + k0 + sa_k + 4);
            f16x8 h;
            h[0] = (_Float16)v0.x; h[1] = (_Float16)v0.y;
            h[2] = (_Float16)v0.z; h[3] = (_Float16)v0.w;
            h[4] = (_Float16)v1.x; h[5] = (_Float16)v1.y;
            h[6] = (_Float16)v1.z; h[7] = (_Float16)v1.w;
            const int bytea = (sa_r * 64 + sa_k * 2) ^ ((sa_r & 7) << 4);
            *(f16x8*)((char*)Ah + bytea) = h;
        }
        {
            const int byteb0 = (sb_c * 64 + sb_k * 2) ^ ((sb_c & 7) << 4);
            const int byteb1 = (sb_c * 64 + sb_k * 2 + 16) ^ ((sb_c & 7) << 4);
            *(uint4*)((char*)Bh + byteb0) =
                *(const uint4*)(BT + (size_t)sb_c * H_ + k0 + sb_k);
            *(uint4*)((char*)Bh + byteb1) =
                *(const uint4*)(BT + (size_t)sb_c * H_ + k0 + sb_k + 8);
        }
        __syncthreads();

        f16x8 af[4], bf[4];
        #pragma unroll
        for (int m = 0; m < 4; ++m) {
            const int r = wm * 64 + m * 16 + l15;
            const int byte = (r * 64 + lq * 16) ^ ((r & 7) << 4);
            af[m] = *(const f16x8*)((const char*)Ah + byte);
        }
        #pragma unroll
        for (int n = 0; n < 4; ++n) {
            const int c = wn * 64 + n * 16 + l15;
            const int byte = (c * 64 + lq * 16) ^ ((c & 7) << 4);
            bf[n] = *(const f16x8*)((const char*)Bh + byte);
        }
        #pragma unroll
        for (int m = 0; m < 4; ++m)
            #pragma unroll
            for (int n = 0; n < 4; ++n)
                acc[m][n] = __builtin_amdgcn_mfma_f32_16x16x32_f16(
                    af[m], bf[n], acc[m][n], 0, 0, 0);
    }

    // epilogue: scores[row] = sum_h relu(acc + base) * W2  (+ b2)
    float basev[4], w2v[4];
    #pragma unroll
    for (int n = 0; n < 4; ++n) {
        const int col = wn * 64 + n * 16 + l15;
        basev[n] = base_[b * H_ + col];
        w2v[n] = W2[col];
    }
    __syncthreads();
    #pragma unroll
    for (int m = 0; m < 4; ++m)
        #pragma unroll
        for (int reg = 0; reg < 4; ++reg) {
            float s = 0.f;
            #pragma unroll
            for (int n = 0; n < 4; ++n) {
                float h = acc[m][n][reg] + basev[n];
                h = fmaxf(h, 0.f);
                s += h * w2v[n];
            }
            s += __shfl_xor(s, 1, 64);
            s += __shfl_xor(s, 2, 64);
            s += __shfl_xor(s, 4, 64);
            s += __shfl_xor(s, 8, 64);
            if (l15 == 0) red[wn][wm * 64 + m * 16 + lq * 4 + reg] = s;
        }
    __syncthreads();
    if (t < 128) {
        scores[row0 + t] = red[0][t] + red[1][t] + red[2][t] + red[3][t] + b2[0];
    }
}

// ---------------------------------------------------------------------------
// Kernel 4: softmax stats per b — m = max_p s, z = sum_p exp(s-m)
// ---------------------------------------------------------------------------
__global__ __launch_bounds__(256) void softmax_stats_kernel(
    const float* __restrict__ scores, float* __restrict__ mz)
{
    const int b = blockIdx.x;
    const int t = threadIdx.x;
    __shared__ float red[8];

    float m = -1e30f;
    for (int p = t; p < P_; p += 256) m = fmaxf(m, scores[b * P_ + p]);
    #pragma unroll
    for (int d = 1; d < 64; d <<= 1) m = fmaxf(m, __shfl_xor(m, d, 64));
    if ((t & 63) == 0) red[t >> 6] = m;
    __syncthreads();
    if (t == 0) red[4] = fmaxf(fmaxf(red[0], red[1]), fmaxf(red[2], red[3]));
    __syncthreads();
    m = red[4];
    __syncthreads();

    float z = 0.f;
    for (int p = t; p < P_; p += 256) z += expf(scores[b * P_ + p] - m);
    #pragma unroll
    for (int d = 1; d < 64; d <<= 1) z += __shfl_xor(z, d, 64);
    if ((t & 63) == 0) red[t >> 6] = z;
    __syncthreads();
    if (t == 0) { mz[2 * b] = m; mz[2 * b + 1] = red[0] + red[1] + red[2] + red[3]; }
}

// ---------------------------------------------------------------------------
// Kernel 5: weighted partial sums over 128-row slices (float4-vectorized)
// ---------------------------------------------------------------------------
__global__ __launch_bounds__(256) void weighted_partial_kernel(
    const float* __restrict__ wmat, const float* __restrict__ scores,
    const float* __restrict__ mz, float* __restrict__ part)
{
    const int blk = blockIdx.x;
    const int b   = blk >> 5;
    const int sl  = blk & 31;
    const int t   = threadIdx.x;
    const int rg  = t >> 6;
    const int q4  = (t & 63) * 4;
    const float m = mz[2 * b];
    __shared__ float red[4][WQ_];

    float4 acc = {0.f, 0.f, 0.f, 0.f};
    const int p0 = sl * 128 + rg * 32;
    for (int p = p0; p < p0 + 32; ++p) {
        const float e = expf(scores[b * P_ + p] - m);
        const float4 v = *(const float4*)(wmat + ((size_t)b * P_ + p) * WQ_ + q4);
        acc.x += e * v.x; acc.y += e * v.y; acc.z += e * v.z; acc.w += e * v.w;
    }
    *(float4*)&red[rg][q4] = acc;
    __syncthreads();
    part[(size_t)(b * 32 + sl) * WQ_ + t] =
        red[0][t] + red[1][t] + red[2][t] + red[3][t];
}

// ---------------------------------------------------------------------------
// Kernel 6: finalize
// ---------------------------------------------------------------------------
__global__ __launch_bounds__(256) void finalize_kernel(
    const float* __restrict__ part, const float* __restrict__ mz,
    float* __restrict__ out)
{
    const int b = blockIdx.x;
    const int t = threadIdx.x;
    const float z = mz[2 * b + 1];
    float acc = 0.f;
    #pragma unroll
    for (int sl = 0; sl < 32; ++sl) acc += part[(size_t)(b * 32 + sl) * WQ_ + t];
    out[b * WQ_ + t] = acc / z;
}

// ---------------------------------------------------------------------------
extern "C" void kernel_launch(void* const* d_in, const int* in_sizes, int n_in,
                              void* d_out, int out_size, void* d_ws, size_t ws_size,
                              hipStream_t stream) {
    const float* cx = (const float*)d_in[0];
    const float* gx = (const float*)d_in[1];
    const float* wx = (const float*)d_in[2];
    const float* Wc = (const float*)d_in[3];
    const float* bc = (const float*)d_in[4];
    const float* Wg = (const float*)d_in[5];
    const float* bg = (const float*)d_in[6];
    const float* Ww = (const float*)d_in[7];
    const float* bw = (const float*)d_in[8];
    const float* W1 = (const float*)d_in[9];
    const float* b1 = (const float*)d_in[10];
    const float* W2 = (const float*)d_in[11];
    const float* b2 = (const float*)d_in[12];
    float* out = (float*)d_out;

    // workspace layout
    float* ws        = (float*)d_ws;
    float* ws_w      = ws;                               // M_*WQ_
    float* ws_scores = ws_w + (size_t)M_ * WQ_;          // M_
    float* ws_base   = ws_scores + M_;                   // B_*H_
    float* ws_mz     = ws_base + B_ * H_;                // 2*B_
    float* ws_part   = ws_mz + 2 * B_;                   // B_*32*WQ_
    ushort* WwT16    = (ushort*)(ws_part + B_ * 32 * WQ_);   // W_*WQ_ fp16
    ushort* W1T16    = WwT16 + (size_t)W_ * WQ_;             // H_*H_ fp16

    convT16_kernel<<<(W_ / 64) * (WQ_ / 64), 256, 0, stream>>>(Ww, WwT16, W_, WQ_);
    convT16_kernel<<<(H_ / 64) * (H_ / 64), 256, 0, stream>>>(
        W1 + (size_t)(C_ + G_) * H_, W1T16, H_, H_);

    prep_kernel<<<B_, 256, 0, stream>>>(cx, gx, Wc, bc, Wg, bg, W1, b1, ws_base);

    gemm_w_mfma<<<(M_ / 128) * (WQ_ / 128), 256, 0, stream>>>(wx, WwT16, bw, ws_w);

    gemm_scores_mfma<<<M_ / 128, 512, 0, stream>>>(
        ws_w, W1T16, ws_base, W2, b2, ws_scores);

    softmax_stats_kernel<<<B_, 256, 0, stream>>>(ws_scores, ws_mz);

    weighted_partial_kernel<<<B_ * 32, 256, 0, stream>>>(ws_w, ws_scores, ws_mz, ws_part);

    finalize_kernel<<<B_, 256, 0, stream>>>(ws_part, ws_mz, out);
}

// Round 8
// 199.618 us; speedup vs baseline: 2.2425x; 1.1709x over previous
//
#include <hip/hip_runtime.h>
#include <hip/hip_bf16.h>

// Problem constants
#define B_   16
#define C_   64
#define G_   256
#define P_   4096
#define W_   1024
#define H_   256
#define WQ_  256
#define M_   (B_ * P_)   // 65536 flattened (b,p) rows

typedef __attribute__((ext_vector_type(8))) _Float16 f16x8;  // MFMA A/B frag (4 VGPRs)
typedef __attribute__((ext_vector_type(4))) float    f32x4;  // MFMA C/D frag

// ---------------------------------------------------------------------------
// convT16: src[K][N] fp32 -> dst[N][K] fp16 (transposed, RNE via v_cvt_f16_f32)
// grid = (K/64)*(N/64), 256 threads
// ---------------------------------------------------------------------------
__global__ __launch_bounds__(256) void convT16_kernel(
    const float* __restrict__ src, ushort* __restrict__ dst, int K, int N)
{
    __shared__ float tile[64][65];
    const int nb = N >> 6;
    const int k0 = (blockIdx.x / nb) * 64;
    const int n0 = (blockIdx.x % nb) * 64;
    const int t = threadIdx.x;
    #pragma unroll
    for (int i = 0; i < 16; ++i) {
        int e = i * 256 + t;
        int kr = e >> 6, nc = e & 63;
        tile[nc][kr] = src[(size_t)(k0 + kr) * N + n0 + nc];
    }
    __syncthreads();
    #pragma unroll
    for (int i = 0; i < 16; ++i) {
        int e = i * 256 + t;
        int nc = e >> 6, kr = e & 63;
        union { _Float16 h; ushort u; } cv;
        cv.h = (_Float16)tile[nc][kr];
        dst[(size_t)(n0 + nc) * K + k0 + kr] = cv.u;
    }
}

// ---------------------------------------------------------------------------
// Kernel 1: prep — c = cx@Wc+bc, g = gx@Wg+bg, base = c@W1c + g@W1g + b1
// ---------------------------------------------------------------------------
__global__ __launch_bounds__(256) void prep_kernel(
    const float* __restrict__ cx, const float* __restrict__ gx,
    const float* __restrict__ Wc, const float* __restrict__ bc,
    const float* __restrict__ Wg, const float* __restrict__ bg,
    const float* __restrict__ W1, const float* __restrict__ b1,
    float* __restrict__ base_out)
{
    const int b = blockIdx.x;
    const int t = threadIdx.x;
    __shared__ float cxl[C_], gxl[G_], cl[C_], gl[G_];

    if (t < C_) cxl[t] = cx[b * C_ + t];
    gxl[t] = gx[b * G_ + t];
    __syncthreads();

    if (t < C_) {
        float acc = bc[t];
        #pragma unroll 4
        for (int i = 0; i < C_; ++i) acc += cxl[i] * Wc[i * C_ + t];
        cl[t] = acc;
    }
    {
        float acc = bg[t];
        #pragma unroll 4
        for (int i = 0; i < G_; ++i) acc += gxl[i] * Wg[i * G_ + t];
        gl[t] = acc;
    }
    __syncthreads();

    float acc = b1[t];
    #pragma unroll 4
    for (int i = 0; i < C_; ++i) acc += cl[i] * W1[i * H_ + t];
    #pragma unroll 4
    for (int i = 0; i < G_; ++i) acc += gl[i] * W1[(C_ + i) * H_ + t];
    base_out[b * H_ + t] = acc;
}

// ---------------------------------------------------------------------------
// Kernel 2: w GEMM, single-pass fp16 MFMA, FULL-N blocks.
// M=65536,K=1024,N=256. BM=128, BN=256(all), BK=64. 512 thr = 8 waves (2Mx4N),
// wave = 64x64 out = 4x4 frags. R2-proven 2-barrier loop, stage-at-top, no reg
// prefetch (R3/R5: scheduler sinks it). A read+converted ONCE total (R7 read it
// twice); per-thread conversion halved. __launch_bounds__(512,2) pins VGPR cap
// at 256 so frags/staging are NOT spilled or re-read (R6 regression: VGPR=80).
// grid = M/128 = 512
// ---------------------------------------------------------------------------
__global__ __launch_bounds__(512, 2) void gemm_w_mfma(
    const float* __restrict__ A,      // wx  M x 1024 fp32
    const ushort* __restrict__ BT,    // WwT fp16 [256][1024]
    const float* __restrict__ bw,
    float* __restrict__ Cout)         // w  M x 256 fp32
{
    __shared__ __align__(16) ushort Ah[128 * 64];   // 16 KB
    __shared__ __align__(16) ushort Bh[256 * 64];   // 32 KB
    const int t = threadIdx.x;
    const int row0 = blockIdx.x * 128;
    const int lane = t & 63, wave = t >> 6;
    const int wm = wave >> 2, wn = wave & 3;        // 2M x 4N waves
    const int l15 = lane & 15, lq = lane >> 4;

    const int s_ar = t >> 2;            // A row 0..127
    const int s_ak = (t & 3) * 16;      // A k chunk start (16 floats)
    const int s_bc = t >> 1;            // B col 0..255
    const int s_bk = (t & 1) * 32;      // B k half (32 halves)

    f32x4 acc[4][4];
    #pragma unroll
    for (int m = 0; m < 4; ++m)
        #pragma unroll
        for (int n = 0; n < 4; ++n) acc[m][n] = (f32x4){0.f, 0.f, 0.f, 0.f};

    for (int k0 = 0; k0 < W_; k0 += 64) {
        if (k0) __syncthreads();
        // stage A: 16 fp32 -> 16 fp16 (RNE), two b128 writes
        {
            const float* ap = A + (size_t)(row0 + s_ar) * W_ + k0 + s_ak;
            const float4 v0 = *(const float4*)(ap + 0);
            const float4 v1 = *(const float4*)(ap + 4);
            const float4 v2 = *(const float4*)(ap + 8);
            const float4 v3 = *(const float4*)(ap + 12);
            f16x8 h0, h1;
            h0[0] = (_Float16)v0.x; h0[1] = (_Float16)v0.y;
            h0[2] = (_Float16)v0.z; h0[3] = (_Float16)v0.w;
            h0[4] = (_Float16)v1.x; h0[5] = (_Float16)v1.y;
            h0[6] = (_Float16)v1.z; h0[7] = (_Float16)v1.w;
            h1[0] = (_Float16)v2.x; h1[1] = (_Float16)v2.y;
            h1[2] = (_Float16)v2.z; h1[3] = (_Float16)v2.w;
            h1[4] = (_Float16)v3.x; h1[5] = (_Float16)v3.y;
            h1[6] = (_Float16)v3.z; h1[7] = (_Float16)v3.w;
            const int base = s_ar * 128 + s_ak * 2;
            const int swz  = (s_ar & 7) << 4;
            *(f16x8*)((char*)Ah + (base ^ swz)) = h0;
            *(f16x8*)((char*)Ah + ((base + 16) ^ swz)) = h1;
        }
        // stage B: 4 uint4 copies (fp16 pre-converted)
        #pragma unroll
        for (int i = 0; i < 4; ++i) {
            const int kk = s_bk + i * 8;
            const int byte = (s_bc * 128 + kk * 2) ^ ((s_bc & 7) << 4);
            *(uint4*)((char*)Bh + byte) =
                *(const uint4*)(BT + (size_t)s_bc * W_ + k0 + kk);
        }
        __syncthreads();

        #pragma unroll
        for (int ks = 0; ks < 2; ++ks) {
            f16x8 af[4], bf[4];
            #pragma unroll
            for (int m = 0; m < 4; ++m) {
                const int r = wm * 64 + m * 16 + l15;
                const int byte = (r * 128 + ks * 64 + lq * 16) ^ ((r & 7) << 4);
                af[m] = *(const f16x8*)((const char*)Ah + byte);
            }
            #pragma unroll
            for (int n = 0; n < 4; ++n) {
                const int c = wn * 64 + n * 16 + l15;
                const int byte = (c * 128 + ks * 64 + lq * 16) ^ ((c & 7) << 4);
                bf[n] = *(const f16x8*)((const char*)Bh + byte);
            }
            #pragma unroll
            for (int m = 0; m < 4; ++m)
                #pragma unroll
                for (int n = 0; n < 4; ++n)
                    acc[m][n] = __builtin_amdgcn_mfma_f32_16x16x32_f16(
                        af[m], bf[n], acc[m][n], 0, 0, 0);
        }
    }

    // epilogue: C[row][col] = acc + bw[col]
    float bwv[4];
    #pragma unroll
    for (int n = 0; n < 4; ++n) bwv[n] = bw[wn * 64 + n * 16 + l15];
    #pragma unroll
    for (int m = 0; m < 4; ++m)
        #pragma unroll
        for (int reg = 0; reg < 4; ++reg) {
            const size_t r = (size_t)row0 + wm * 64 + m * 16 + lq * 4 + reg;
            #pragma unroll
            for (int n = 0; n < 4; ++n)
                Cout[r * WQ_ + wn * 64 + n * 16 + l15] = acc[m][n][reg] + bwv[n];
        }
}

// ---------------------------------------------------------------------------
// Kernel 3: scores, single-pass fp16 MFMA + fused relu/dot(W2) epilogue.
// M=65536,K=256(q),N=256(h). BM=128, BN=256(all), BK=32, 512 thr, 8 waves (2x4).
// grid = M/128 = 512   (unchanged from R7 — it passed and is small)
// ---------------------------------------------------------------------------
__global__ __launch_bounds__(512) void gemm_scores_mfma(
    const float* __restrict__ A,      // w M x 256 fp32
    const ushort* __restrict__ BT,    // W1wT fp16 [256][256]
    const float* __restrict__ base_,  // B_ x 256
    const float* __restrict__ W2,     // 256
    const float* __restrict__ b2,     // 1
    float* __restrict__ scores)       // M
{
    __shared__ __align__(16) ushort Ah[128 * 32];   // 8 KB
    __shared__ __align__(16) ushort Bh[256 * 32];   // 16 KB
    __shared__ float red[4][128];
    const int t = threadIdx.x;
    const int row0 = blockIdx.x * 128;
    const int b = blockIdx.x >> 5;            // 32 blocks per batch
    const int lane = t & 63, wave = t >> 6;
    const int wm = wave >> 2, wn = wave & 3;
    const int l15 = lane & 15, lq = lane >> 4;

    const int sa_r = t >> 2;            // A row 0..127
    const int sa_k = (t & 3) * 8;       // A k chunk (8 elems)
    const int sb_c = t >> 1;            // B col 0..255
    const int sb_k = (t & 1) * 16;      // B k half (16 elems)

    f32x4 acc[4][4];
    #pragma unroll
    for (int m = 0; m < 4; ++m)
        #pragma unroll
        for (int n = 0; n < 4; ++n) acc[m][n] = (f32x4){0.f, 0.f, 0.f, 0.f};

    for (int k0 = 0; k0 < H_; k0 += 32) {
        if (k0) __syncthreads();
        {
            const float4 v0 = *(const float4*)(A + (size_t)(row0 + sa_r) * H_ + k0 + sa_k);
            const float4 v1 = *(const float4*)(A + (size_t)(row0 + sa_r) * H_ + k0 + sa_k + 4);
            f16x8 h;
            h[0] = (_Float16)v0.x; h[1] = (_Float16)v0.y;
            h[2] = (_Float16)v0.z; h[3] = (_Float16)v0.w;
            h[4] = (_Float16)v1.x; h[5] = (_Float16)v1.y;
            h[6] = (_Float16)v1.z; h[7] = (_Float16)v1.w;
            const int bytea = (sa_r * 64 + sa_k * 2) ^ ((sa_r & 7) << 4);
            *(f16x8*)((char*)Ah + bytea) = h;
        }
        {
            const int byteb0 = (sb_c * 64 + sb_k * 2) ^ ((sb_c & 7) << 4);
            const int byteb1 = (sb_c * 64 + sb_k * 2 + 16) ^ ((sb_c & 7) << 4);
            *(uint4*)((char*)Bh + byteb0) =
                *(const uint4*)(BT + (size_t)sb_c * H_ + k0 + sb_k);
            *(uint4*)((char*)Bh + byteb1) =
                *(const uint4*)(BT + (size_t)sb_c * H_ + k0 + sb_k + 8);
        }
        __syncthreads();

        f16x8 af[4], bf[4];
        #pragma unroll
        for (int m = 0; m < 4; ++m) {
            const int r = wm * 64 + m * 16 + l15;
            const int byte = (r * 64 + lq * 16) ^ ((r & 7) << 4);
            af[m] = *(const f16x8*)((const char*)Ah + byte);
        }
        #pragma unroll
        for (int n = 0; n < 4; ++n) {
            const int c = wn * 64 + n * 16 + l15;
            const int byte = (c * 64 + lq * 16) ^ ((c & 7) << 4);
            bf[n] = *(const f16x8*)((const char*)Bh + byte);
        }
        #pragma unroll
        for (int m = 0; m < 4; ++m)
            #pragma unroll
            for (int n = 0; n < 4; ++n)
                acc[m][n] = __builtin_amdgcn_mfma_f32_16x16x32_f16(
                    af[m], bf[n], acc[m][n], 0, 0, 0);
    }

    // epilogue: scores[row] = sum_h relu(acc + base) * W2  (+ b2)
    float basev[4], w2v[4];
    #pragma unroll
    for (int n = 0; n < 4; ++n) {
        const int col = wn * 64 + n * 16 + l15;
        basev[n] = base_[b * H_ + col];
        w2v[n] = W2[col];
    }
    __syncthreads();
    #pragma unroll
    for (int m = 0; m < 4; ++m)
        #pragma unroll
        for (int reg = 0; reg < 4; ++reg) {
            float s = 0.f;
            #pragma unroll
            for (int n = 0; n < 4; ++n) {
                float h = acc[m][n][reg] + basev[n];
                h = fmaxf(h, 0.f);
                s += h * w2v[n];
            }
            s += __shfl_xor(s, 1, 64);
            s += __shfl_xor(s, 2, 64);
            s += __shfl_xor(s, 4, 64);
            s += __shfl_xor(s, 8, 64);
            if (l15 == 0) red[wn][wm * 64 + m * 16 + lq * 4 + reg] = s;
        }
    __syncthreads();
    if (t < 128) {
        scores[row0 + t] = red[0][t] + red[1][t] + red[2][t] + red[3][t] + b2[0];
    }
}

// ---------------------------------------------------------------------------
// Kernel 4: softmax stats per b — m = max_p s, z = sum_p exp(s-m)
// ---------------------------------------------------------------------------
__global__ __launch_bounds__(256) void softmax_stats_kernel(
    const float* __restrict__ scores, float* __restrict__ mz)
{
    const int b = blockIdx.x;
    const int t = threadIdx.x;
    __shared__ float red[8];

    float m = -1e30f;
    for (int p = t; p < P_; p += 256) m = fmaxf(m, scores[b * P_ + p]);
    #pragma unroll
    for (int d = 1; d < 64; d <<= 1) m = fmaxf(m, __shfl_xor(m, d, 64));
    if ((t & 63) == 0) red[t >> 6] = m;
    __syncthreads();
    if (t == 0) red[4] = fmaxf(fmaxf(red[0], red[1]), fmaxf(red[2], red[3]));
    __syncthreads();
    m = red[4];
    __syncthreads();

    float z = 0.f;
    for (int p = t; p < P_; p += 256) z += expf(scores[b * P_ + p] - m);
    #pragma unroll
    for (int d = 1; d < 64; d <<= 1) z += __shfl_xor(z, d, 64);
    if ((t & 63) == 0) red[t >> 6] = z;
    __syncthreads();
    if (t == 0) { mz[2 * b] = m; mz[2 * b + 1] = red[0] + red[1] + red[2] + red[3]; }
}

// ---------------------------------------------------------------------------
// Kernel 5: weighted partial sums over 128-row slices (float4-vectorized)
// ---------------------------------------------------------------------------
__global__ __launch_bounds__(256) void weighted_partial_kernel(
    const float* __restrict__ wmat, const float* __restrict__ scores,
    const float* __restrict__ mz, float* __restrict__ part)
{
    const int blk = blockIdx.x;
    const int b   = blk >> 5;
    const int sl  = blk & 31;
    const int t   = threadIdx.x;
    const int rg  = t >> 6;
    const int q4  = (t & 63) * 4;
    const float m = mz[2 * b];
    __shared__ float red[4][WQ_];

    float4 acc = {0.f, 0.f, 0.f, 0.f};
    const int p0 = sl * 128 + rg * 32;
    for (int p = p0; p < p0 + 32; ++p) {
        const float e = expf(scores[b * P_ + p] - m);
        const float4 v = *(const float4*)(wmat + ((size_t)b * P_ + p) * WQ_ + q4);
        acc.x += e * v.x; acc.y += e * v.y; acc.z += e * v.z; acc.w += e * v.w;
    }
    *(float4*)&red[rg][q4] = acc;
    __syncthreads();
    part[(size_t)(b * 32 + sl) * WQ_ + t] =
        red[0][t] + red[1][t] + red[2][t] + red[3][t];
}

// ---------------------------------------------------------------------------
// Kernel 6: finalize
// ---------------------------------------------------------------------------
__global__ __launch_bounds__(256) void finalize_kernel(
    const float* __restrict__ part, const float* __restrict__ mz,
    float* __restrict__ out)
{
    const int b = blockIdx.x;
    const int t = threadIdx.x;
    const float z = mz[2 * b + 1];
    float acc = 0.f;
    #pragma unroll
    for (int sl = 0; sl < 32; ++sl) acc += part[(size_t)(b * 32 + sl) * WQ_ + t];
    out[b * WQ_ + t] = acc / z;
}

// ---------------------------------------------------------------------------
extern "C" void kernel_launch(void* const* d_in, const int* in_sizes, int n_in,
                              void* d_out, int out_size, void* d_ws, size_t ws_size,
                              hipStream_t stream) {
    const float* cx = (const float*)d_in[0];
    const float* gx = (const float*)d_in[1];
    const float* wx = (const float*)d_in[2];
    const float* Wc = (const float*)d_in[3];
    const float* bc = (const float*)d_in[4];
    const float* Wg = (const float*)d_in[5];
    const float* bg = (const float*)d_in[6];
    const float* Ww = (const float*)d_in[7];
    const float* bw = (const float*)d_in[8];
    const float* W1 = (const float*)d_in[9];
    const float* b1 = (const float*)d_in[10];
    const float* W2 = (const float*)d_in[11];
    const float* b2 = (const float*)d_in[12];
    float* out = (float*)d_out;

    // workspace layout
    float* ws        = (float*)d_ws;
    float* ws_w      = ws;                               // M_*WQ_
    float* ws_scores = ws_w + (size_t)M_ * WQ_;          // M_
    float* ws_base   = ws_scores + M_;                   // B_*H_
    float* ws_mz     = ws_base + B_ * H_;                // 2*B_
    float* ws_part   = ws_mz + 2 * B_;                   // B_*32*WQ_
    ushort* WwT16    = (ushort*)(ws_part + B_ * 32 * WQ_);   // W_*WQ_ fp16
    ushort* W1T16    = WwT16 + (size_t)W_ * WQ_;             // H_*H_ fp16

    convT16_kernel<<<(W_ / 64) * (WQ_ / 64), 256, 0, stream>>>(Ww, WwT16, W_, WQ_);
    convT16_kernel<<<(H_ / 64) * (H_ / 64), 256, 0, stream>>>(
        W1 + (size_t)(C_ + G_) * H_, W1T16, H_, H_);

    prep_kernel<<<B_, 256, 0, stream>>>(cx, gx, Wc, bc, Wg, bg, W1, b1, ws_base);

    gemm_w_mfma<<<M_ / 128, 512, 0, stream>>>(wx, WwT16, bw, ws_w);

    gemm_scores_mfma<<<M_ / 128, 512, 0, stream>>>(
        ws_w, W1T16, ws_base, W2, b2, ws_scores);

    softmax_stats_kernel<<<B_, 256, 0, stream>>>(ws_scores, ws_mz);

    weighted_partial_kernel<<<B_ * 32, 256, 0, stream>>>(ws_w, ws_scores, ws_mz, ws_part);

    finalize_kernel<<<B_, 256, 0, stream>>>(ws_part, ws_mz, out);
}

// Round 9
// 187.203 us; speedup vs baseline: 2.3912x; 1.0663x over previous
//
#include <hip/hip_runtime.h>
#include <hip/hip_bf16.h>

// Problem constants
#define B_   16
#define C_   64
#define G_   256
#define P_   4096
#define W_   1024
#define H_   256
#define WQ_  256
#define M_   (B_ * P_)   // 65536 flattened (b,p) rows

typedef __attribute__((ext_vector_type(8))) _Float16 f16x8;  // MFMA A/B frag (4 VGPRs)
typedef __attribute__((ext_vector_type(4))) float    f32x4;  // MFMA C/D frag

__device__ __forceinline__ float h2f(ushort u) {
    union { ushort u; _Float16 h; } cv; cv.u = u;
    return (float)cv.h;
}

// ---------------------------------------------------------------------------
// convT16: src[K][N] fp32 -> dst[N][K] fp16 (transposed, RNE via v_cvt_f16_f32)
// grid = (K/64)*(N/64), 256 threads
// ---------------------------------------------------------------------------
__global__ __launch_bounds__(256) void convT16_kernel(
    const float* __restrict__ src, ushort* __restrict__ dst, int K, int N)
{
    __shared__ float tile[64][65];
    const int nb = N >> 6;
    const int k0 = (blockIdx.x / nb) * 64;
    const int n0 = (blockIdx.x % nb) * 64;
    const int t = threadIdx.x;
    #pragma unroll
    for (int i = 0; i < 16; ++i) {
        int e = i * 256 + t;
        int kr = e >> 6, nc = e & 63;
        tile[nc][kr] = src[(size_t)(k0 + kr) * N + n0 + nc];
    }
    __syncthreads();
    #pragma unroll
    for (int i = 0; i < 16; ++i) {
        int e = i * 256 + t;
        int nc = e >> 6, kr = e & 63;
        union { _Float16 h; ushort u; } cv;
        cv.h = (_Float16)tile[nc][kr];
        dst[(size_t)(n0 + nc) * K + k0 + kr] = cv.u;
    }
}

// ---------------------------------------------------------------------------
// Kernel 1: prep — c = cx@Wc+bc, g = gx@Wg+bg, base = c@W1c + g@W1g + b1
// ---------------------------------------------------------------------------
__global__ __launch_bounds__(256) void prep_kernel(
    const float* __restrict__ cx, const float* __restrict__ gx,
    const float* __restrict__ Wc, const float* __restrict__ bc,
    const float* __restrict__ Wg, const float* __restrict__ bg,
    const float* __restrict__ W1, const float* __restrict__ b1,
    float* __restrict__ base_out)
{
    const int b = blockIdx.x;
    const int t = threadIdx.x;
    __shared__ float cxl[C_], gxl[G_], cl[C_], gl[G_];

    if (t < C_) cxl[t] = cx[b * C_ + t];
    gxl[t] = gx[b * G_ + t];
    __syncthreads();

    if (t < C_) {
        float acc = bc[t];
        #pragma unroll 4
        for (int i = 0; i < C_; ++i) acc += cxl[i] * Wc[i * C_ + t];
        cl[t] = acc;
    }
    {
        float acc = bg[t];
        #pragma unroll 4
        for (int i = 0; i < G_; ++i) acc += gxl[i] * Wg[i * G_ + t];
        gl[t] = acc;
    }
    __syncthreads();

    float acc = b1[t];
    #pragma unroll 4
    for (int i = 0; i < C_; ++i) acc += cl[i] * W1[i * H_ + t];
    #pragma unroll 4
    for (int i = 0; i < G_; ++i) acc += gl[i] * W1[(C_ + i) * H_ + t];
    base_out[b * H_ + t] = acc;
}

// ---------------------------------------------------------------------------
// Kernel 2: w GEMM, single-pass fp16 MFMA, FULL-N blocks, fp16 OUTPUT.
// M=65536,K=1024,N=256. BM=128, BN=256(all), BK=64. 512 thr = 8 waves (2Mx4N).
// Output stored as fp16 (w is consumed fp16 by scores anyway; weighted sum
// tolerates 2^-11 rounding) — halves w write + all downstream w reads.
// grid = M/128 = 512
// ---------------------------------------------------------------------------
__global__ __launch_bounds__(512, 2) void gemm_w_mfma(
    const float* __restrict__ A,      // wx  M x 1024 fp32
    const ushort* __restrict__ BT,    // WwT fp16 [256][1024]
    const float* __restrict__ bw,
    ushort* __restrict__ Cout)        // w  M x 256 fp16
{
    __shared__ __align__(16) ushort Ah[128 * 64];   // 16 KB
    __shared__ __align__(16) ushort Bh[256 * 64];   // 32 KB
    const int t = threadIdx.x;
    const int row0 = blockIdx.x * 128;
    const int lane = t & 63, wave = t >> 6;
    const int wm = wave >> 2, wn = wave & 3;        // 2M x 4N waves
    const int l15 = lane & 15, lq = lane >> 4;

    const int s_ar = t >> 2;            // A row 0..127
    const int s_ak = (t & 3) * 16;      // A k chunk start (16 floats)
    const int s_bc = t >> 1;            // B col 0..255
    const int s_bk = (t & 1) * 32;      // B k half (32 halves)

    f32x4 acc[4][4];
    #pragma unroll
    for (int m = 0; m < 4; ++m)
        #pragma unroll
        for (int n = 0; n < 4; ++n) acc[m][n] = (f32x4){0.f, 0.f, 0.f, 0.f};

    for (int k0 = 0; k0 < W_; k0 += 64) {
        if (k0) __syncthreads();
        // stage A: 16 fp32 -> 16 fp16 (RNE), two b128 writes
        {
            const float* ap = A + (size_t)(row0 + s_ar) * W_ + k0 + s_ak;
            const float4 v0 = *(const float4*)(ap + 0);
            const float4 v1 = *(const float4*)(ap + 4);
            const float4 v2 = *(const float4*)(ap + 8);
            const float4 v3 = *(const float4*)(ap + 12);
            f16x8 h0, h1;
            h0[0] = (_Float16)v0.x; h0[1] = (_Float16)v0.y;
            h0[2] = (_Float16)v0.z; h0[3] = (_Float16)v0.w;
            h0[4] = (_Float16)v1.x; h0[5] = (_Float16)v1.y;
            h0[6] = (_Float16)v1.z; h0[7] = (_Float16)v1.w;
            h1[0] = (_Float16)v2.x; h1[1] = (_Float16)v2.y;
            h1[2] = (_Float16)v2.z; h1[3] = (_Float16)v2.w;
            h1[4] = (_Float16)v3.x; h1[5] = (_Float16)v3.y;
            h1[6] = (_Float16)v3.z; h1[7] = (_Float16)v3.w;
            const int base = s_ar * 128 + s_ak * 2;
            const int swz  = (s_ar & 7) << 4;
            *(f16x8*)((char*)Ah + (base ^ swz)) = h0;
            *(f16x8*)((char*)Ah + ((base + 16) ^ swz)) = h1;
        }
        // stage B: 4 uint4 copies (fp16 pre-converted)
        #pragma unroll
        for (int i = 0; i < 4; ++i) {
            const int kk = s_bk + i * 8;
            const int byte = (s_bc * 128 + kk * 2) ^ ((s_bc & 7) << 4);
            *(uint4*)((char*)Bh + byte) =
                *(const uint4*)(BT + (size_t)s_bc * W_ + k0 + kk);
        }
        __syncthreads();

        #pragma unroll
        for (int ks = 0; ks < 2; ++ks) {
            f16x8 af[4], bf[4];
            #pragma unroll
            for (int m = 0; m < 4; ++m) {
                const int r = wm * 64 + m * 16 + l15;
                const int byte = (r * 128 + ks * 64 + lq * 16) ^ ((r & 7) << 4);
                af[m] = *(const f16x8*)((const char*)Ah + byte);
            }
            #pragma unroll
            for (int n = 0; n < 4; ++n) {
                const int c = wn * 64 + n * 16 + l15;
                const int byte = (c * 128 + ks * 64 + lq * 16) ^ ((c & 7) << 4);
                bf[n] = *(const f16x8*)((const char*)Bh + byte);
            }
            #pragma unroll
            for (int m = 0; m < 4; ++m)
                #pragma unroll
                for (int n = 0; n < 4; ++n)
                    acc[m][n] = __builtin_amdgcn_mfma_f32_16x16x32_f16(
                        af[m], bf[n], acc[m][n], 0, 0, 0);
        }
    }

    // epilogue: w16[row][col] = fp16(acc + bw[col])
    float bwv[4];
    #pragma unroll
    for (int n = 0; n < 4; ++n) bwv[n] = bw[wn * 64 + n * 16 + l15];
    #pragma unroll
    for (int m = 0; m < 4; ++m)
        #pragma unroll
        for (int reg = 0; reg < 4; ++reg) {
            const size_t r = (size_t)row0 + wm * 64 + m * 16 + lq * 4 + reg;
            #pragma unroll
            for (int n = 0; n < 4; ++n) {
                union { _Float16 h; ushort u; } cv;
                cv.h = (_Float16)(acc[m][n][reg] + bwv[n]);
                Cout[r * WQ_ + wn * 64 + n * 16 + l15] = cv.u;
            }
        }
}

// ---------------------------------------------------------------------------
// Kernel 3: scores — A (w) is already fp16: staging is a pure copy, no cvt.
// M=65536,K=256(q),N=256(h). BM=128, BN=256(all), BK=32, 512 thr, 8 waves (2x4).
// grid = M/128 = 512
// ---------------------------------------------------------------------------
__global__ __launch_bounds__(512) void gemm_scores_mfma(
    const ushort* __restrict__ A16,   // w M x 256 fp16
    const ushort* __restrict__ BT,    // W1wT fp16 [256][256]
    const float* __restrict__ base_,  // B_ x 256
    const float* __restrict__ W2,     // 256
    const float* __restrict__ b2,     // 1
    float* __restrict__ scores)       // M
{
    __shared__ __align__(16) ushort Ah[128 * 32];   // 8 KB
    __shared__ __align__(16) ushort Bh[256 * 32];   // 16 KB
    __shared__ float red[4][128];
    const int t = threadIdx.x;
    const int row0 = blockIdx.x * 128;
    const int b = blockIdx.x >> 5;            // 32 blocks per batch
    const int lane = t & 63, wave = t >> 6;
    const int wm = wave >> 2, wn = wave & 3;
    const int l15 = lane & 15, lq = lane >> 4;

    const int sa_r = t >> 2;            // A row 0..127
    const int sa_k = (t & 3) * 8;       // A k chunk (8 halves)
    const int sb_c = t >> 1;            // B col 0..255
    const int sb_k = (t & 1) * 16;      // B k half (16 halves)

    f32x4 acc[4][4];
    #pragma unroll
    for (int m = 0; m < 4; ++m)
        #pragma unroll
        for (int n = 0; n < 4; ++n) acc[m][n] = (f32x4){0.f, 0.f, 0.f, 0.f};

    for (int k0 = 0; k0 < H_; k0 += 32) {
        if (k0) __syncthreads();
        {
            const int bytea = (sa_r * 64 + sa_k * 2) ^ ((sa_r & 7) << 4);
            *(uint4*)((char*)Ah + bytea) =
                *(const uint4*)(A16 + (size_t)(row0 + sa_r) * H_ + k0 + sa_k);
        }
        {
            const int byteb0 = (sb_c * 64 + sb_k * 2) ^ ((sb_c & 7) << 4);
            const int byteb1 = (sb_c * 64 + sb_k * 2 + 16) ^ ((sb_c & 7) << 4);
            *(uint4*)((char*)Bh + byteb0) =
                *(const uint4*)(BT + (size_t)sb_c * H_ + k0 + sb_k);
            *(uint4*)((char*)Bh + byteb1) =
                *(const uint4*)(BT + (size_t)sb_c * H_ + k0 + sb_k + 8);
        }
        __syncthreads();

        f16x8 af[4], bf[4];
        #pragma unroll
        for (int m = 0; m < 4; ++m) {
            const int r = wm * 64 + m * 16 + l15;
            const int byte = (r * 64 + lq * 16) ^ ((r & 7) << 4);
            af[m] = *(const f16x8*)((const char*)Ah + byte);
        }
        #pragma unroll
        for (int n = 0; n < 4; ++n) {
            const int c = wn * 64 + n * 16 + l15;
            const int byte = (c * 64 + lq * 16) ^ ((c & 7) << 4);
            bf[n] = *(const f16x8*)((const char*)Bh + byte);
        }
        #pragma unroll
        for (int m = 0; m < 4; ++m)
            #pragma unroll
            for (int n = 0; n < 4; ++n)
                acc[m][n] = __builtin_amdgcn_mfma_f32_16x16x32_f16(
                    af[m], bf[n], acc[m][n], 0, 0, 0);
    }

    // epilogue: scores[row] = sum_h relu(acc + base) * W2  (+ b2)
    float basev[4], w2v[4];
    #pragma unroll
    for (int n = 0; n < 4; ++n) {
        const int col = wn * 64 + n * 16 + l15;
        basev[n] = base_[b * H_ + col];
        w2v[n] = W2[col];
    }
    __syncthreads();
    #pragma unroll
    for (int m = 0; m < 4; ++m)
        #pragma unroll
        for (int reg = 0; reg < 4; ++reg) {
            float s = 0.f;
            #pragma unroll
            for (int n = 0; n < 4; ++n) {
                float h = acc[m][n][reg] + basev[n];
                h = fmaxf(h, 0.f);
                s += h * w2v[n];
            }
            s += __shfl_xor(s, 1, 64);
            s += __shfl_xor(s, 2, 64);
            s += __shfl_xor(s, 4, 64);
            s += __shfl_xor(s, 8, 64);
            if (l15 == 0) red[wn][wm * 64 + m * 16 + lq * 4 + reg] = s;
        }
    __syncthreads();
    if (t < 128) {
        scores[row0 + t] = red[0][t] + red[1][t] + red[2][t] + red[3][t] + b2[0];
    }
}

// ---------------------------------------------------------------------------
// Kernel 4: softmax stats per b — m = max_p s, z = sum_p exp(s-m)
// ---------------------------------------------------------------------------
__global__ __launch_bounds__(256) void softmax_stats_kernel(
    const float* __restrict__ scores, float* __restrict__ mz)
{
    const int b = blockIdx.x;
    const int t = threadIdx.x;
    __shared__ float red[8];

    float m = -1e30f;
    for (int p = t; p < P_; p += 256) m = fmaxf(m, scores[b * P_ + p]);
    #pragma unroll
    for (int d = 1; d < 64; d <<= 1) m = fmaxf(m, __shfl_xor(m, d, 64));
    if ((t & 63) == 0) red[t >> 6] = m;
    __syncthreads();
    if (t == 0) red[4] = fmaxf(fmaxf(red[0], red[1]), fmaxf(red[2], red[3]));
    __syncthreads();
    m = red[4];
    __syncthreads();

    float z = 0.f;
    for (int p = t; p < P_; p += 256) z += expf(scores[b * P_ + p] - m);
    #pragma unroll
    for (int d = 1; d < 64; d <<= 1) z += __shfl_xor(z, d, 64);
    if ((t & 63) == 0) red[t >> 6] = z;
    __syncthreads();
    if (t == 0) { mz[2 * b] = m; mz[2 * b + 1] = red[0] + red[1] + red[2] + red[3]; }
}

// ---------------------------------------------------------------------------
// Kernel 5: weighted partial sums over 128-row slices (fp16 w, ushort8 loads)
// grid = B_*32, 256 threads: rg = t>>5 picks 16-row subgroup, (t&31)*8 = q8
// ---------------------------------------------------------------------------
__global__ __launch_bounds__(256) void weighted_partial_kernel(
    const ushort* __restrict__ wmat16, const float* __restrict__ scores,
    const float* __restrict__ mz, float* __restrict__ part)
{
    const int blk = blockIdx.x;
    const int b   = blk >> 5;
    const int sl  = blk & 31;
    const int t   = threadIdx.x;
    const int rg  = t >> 5;            // 0..7
    const int q8  = (t & 31) * 8;      // 0..248
    const float m = mz[2 * b];
    __shared__ float red[8][WQ_];

    float acc[8];
    #pragma unroll
    for (int j = 0; j < 8; ++j) acc[j] = 0.f;

    const int p0 = sl * 128 + rg * 16;
    for (int p = p0; p < p0 + 16; ++p) {
        const float e = expf(scores[b * P_ + p] - m);
        const uint4 raw = *(const uint4*)(wmat16 + ((size_t)b * P_ + p) * WQ_ + q8);
        const ushort* u = (const ushort*)&raw;
        #pragma unroll
        for (int j = 0; j < 8; ++j) acc[j] += e * h2f(u[j]);
    }
    #pragma unroll
    for (int j = 0; j < 8; ++j) red[rg][q8 + j] = acc[j];
    __syncthreads();
    float s = 0.f;
    #pragma unroll
    for (int g = 0; g < 8; ++g) s += red[g][t];
    part[(size_t)(b * 32 + sl) * WQ_ + t] = s;
}

// ---------------------------------------------------------------------------
// Kernel 6: finalize
// ---------------------------------------------------------------------------
__global__ __launch_bounds__(256) void finalize_kernel(
    const float* __restrict__ part, const float* __restrict__ mz,
    float* __restrict__ out)
{
    const int b = blockIdx.x;
    const int t = threadIdx.x;
    const float z = mz[2 * b + 1];
    float acc = 0.f;
    #pragma unroll
    for (int sl = 0; sl < 32; ++sl) acc += part[(size_t)(b * 32 + sl) * WQ_ + t];
    out[b * WQ_ + t] = acc / z;
}

// ---------------------------------------------------------------------------
extern "C" void kernel_launch(void* const* d_in, const int* in_sizes, int n_in,
                              void* d_out, int out_size, void* d_ws, size_t ws_size,
                              hipStream_t stream) {
    const float* cx = (const float*)d_in[0];
    const float* gx = (const float*)d_in[1];
    const float* wx = (const float*)d_in[2];
    const float* Wc = (const float*)d_in[3];
    const float* bc = (const float*)d_in[4];
    const float* Wg = (const float*)d_in[5];
    const float* bg = (const float*)d_in[6];
    const float* Ww = (const float*)d_in[7];
    const float* bw = (const float*)d_in[8];
    const float* W1 = (const float*)d_in[9];
    const float* b1 = (const float*)d_in[10];
    const float* W2 = (const float*)d_in[11];
    const float* b2 = (const float*)d_in[12];
    float* out = (float*)d_out;

    // workspace layout
    float* ws        = (float*)d_ws;
    ushort* ws_w16   = (ushort*)ws;                      // M_*WQ_ fp16 (32 MB)
    float* ws_scores = ws + (size_t)M_ * WQ_ / 2;        // M_
    float* ws_base   = ws_scores + M_;                   // B_*H_
    float* ws_mz     = ws_base + B_ * H_;                // 2*B_
    float* ws_part   = ws_mz + 2 * B_;                   // B_*32*WQ_
    ushort* WwT16    = (ushort*)(ws_part + B_ * 32 * WQ_);   // W_*WQ_ fp16
    ushort* W1T16    = WwT16 + (size_t)W_ * WQ_;             // H_*H_ fp16

    convT16_kernel<<<(W_ / 64) * (WQ_ / 64), 256, 0, stream>>>(Ww, WwT16, W_, WQ_);
    convT16_kernel<<<(H_ / 64) * (H_ / 64), 256, 0, stream>>>(
        W1 + (size_t)(C_ + G_) * H_, W1T16, H_, H_);

    prep_kernel<<<B_, 256, 0, stream>>>(cx, gx, Wc, bc, Wg, bg, W1, b1, ws_base);

    gemm_w_mfma<<<M_ / 128, 512, 0, stream>>>(wx, WwT16, bw, ws_w16);

    gemm_scores_mfma<<<M_ / 128, 512, 0, stream>>>(
        ws_w16, W1T16, ws_base, W2, b2, ws_scores);

    softmax_stats_kernel<<<B_, 256, 0, stream>>>(ws_scores, ws_mz);

    weighted_partial_kernel<<<B_ * 32, 256, 0, stream>>>(ws_w16, ws_scores, ws_mz, ws_part);

    finalize_kernel<<<B_, 256, 0, stream>>>(ws_part, ws_mz, out);
}